// Round 1
// baseline (4263.587 us; speedup 1.0000x reference)
//
#include <hip/hip_runtime.h>

#define N_NODES 100000
#define N_EDGES 1600000

typedef float4 f4;

// ---------------- degree ----------------
__global__ __launch_bounds__(256) void k_deg(const int* __restrict__ dst, float* __restrict__ deg) {
  int i = blockIdx.x * 256 + threadIdx.x;
  if (i < N_EDGES) atomicAdd(&deg[dst[i]], 1.0f);
}

__global__ __launch_bounds__(256) void k_invdeg(float* __restrict__ deg) {
  int i = blockIdx.x * 256 + threadIdx.x;
  if (i < N_NODES) deg[i] = 1.0f / fmaxf(deg[i], 1.0f);
}

// ------------- combined projection weights for final layer -------------
// Wcl = Wl2[:,64:] @ Wf   (40x128), Wcr = Wr2[:,64:] @ Wf
// bc[0:40] = Wl2[:,64:] @ bf ; bc[40:80] = Wr2[:,64:] @ bf + b2
__global__ void k_precomp(const float* __restrict__ Wl2, const float* __restrict__ Wr2,
                          const float* __restrict__ Wf, const float* __restrict__ bfv,
                          const float* __restrict__ b2,
                          float* __restrict__ Wcl, float* __restrict__ Wcr, float* __restrict__ bc) {
  int o = blockIdx.x, k = threadIdx.x;  // o<40, k<128
  float al = 0.f, ar = 0.f;
  for (int j = 0; j < 64; ++j) {
    float wl = Wl2[o*128 + 64 + j], wr = Wr2[o*128 + 64 + j];
    float wf = Wf[j*128 + k];
    al = fmaf(wl, wf, al); ar = fmaf(wr, wf, ar);
  }
  Wcl[o*128 + k] = al; Wcr[o*128 + k] = ar;
  if (k == 0) {
    float sl = 0.f, sr = 0.f;
    for (int j = 0; j < 64; ++j) { sl += Wl2[o*128+64+j]*bfv[j]; sr += Wr2[o*128+64+j]*bfv[j]; }
    bc[o] = sl; bc[40+o] = sr + b2[o];
  }
}

// transposed weight blob [K][128]: col c<64 -> W1 row c, else W2 row c-64
template<int K>
__global__ __launch_bounds__(256) void k_buildwt(const float* __restrict__ W1, const float* __restrict__ W2,
                                                 float* __restrict__ dst) {
  int idx = blockIdx.x * 256 + threadIdx.x;
  if (idx >= K*128) return;
  int c = idx & 127, k = idx >> 7;
  dst[idx] = (c < 64) ? W1[c*K + k] : W2[(c-64)*K + k];
}

// final blob [192][80]
__global__ __launch_bounds__(256) void k_buildwtf(const float* __restrict__ Wl2, const float* __restrict__ Wr2,
                                                  const float* __restrict__ Wcl, const float* __restrict__ Wcr,
                                                  float* __restrict__ dst) {
  int idx = blockIdx.x * 256 + threadIdx.x;
  if (idx >= 192*80) return;
  int c = idx % 80, k = idx / 80;
  float w;
  if (k < 64) w = (c < 40) ? Wl2[c*128 + k] : Wr2[(c-40)*128 + k];
  else        w = (c < 40) ? Wcl[c*128 + k-64] : Wcr[(c-40)*128 + k-64];
  dst[idx] = w;
}

// ------------- dual GEMM: out1 = in@W1.T, out2 = in@W2.T + bias2 -------------
// wtg is pre-transposed [K][128] (c<64 -> W1, c>=64 -> W2). Optional fused BN+ReLU on input.
template<int K, bool BN>
__global__ __launch_bounds__(256) void k_gemm_dual(
    const float* __restrict__ in, const float* __restrict__ ss,
    const float* __restrict__ wtg, const float* __restrict__ bias2,
    float* __restrict__ out1, float* __restrict__ out2) {
  __shared__ float wt[K*128];
  __shared__ float xs[32*K];
  const int tx = threadIdx.x;
  for (int i = tx; i < K*32; i += 256) ((f4*)wt)[i] = ((const f4*)wtg)[i];
  const int row0 = blockIdx.x * 32;
  for (int i = tx; i < 32*(K/4); i += 256) {
    int row = i / (K/4), kq = i % (K/4);
    int grow = row0 + row;
    f4 v = {0.f,0.f,0.f,0.f};
    if (grow < N_NODES) {
      v = *(const f4*)&in[grow*K + kq*4];
      if (BN) {
        int c = kq*4;
        v.x = fmaxf(0.f, fmaf(v.x, ss[c+0], ss[K+c+0]));
        v.y = fmaxf(0.f, fmaf(v.y, ss[c+1], ss[K+c+1]));
        v.z = fmaxf(0.f, fmaf(v.z, ss[c+2], ss[K+c+2]));
        v.w = fmaxf(0.f, fmaf(v.w, ss[c+3], ss[K+c+3]));
      }
    }
    *(f4*)&xs[row*K + kq*4] = v;
  }
  __syncthreads();
  const int c0 = (tx & 31) * 4;   // 0..124 (128 output channels)
  const int r0 = (tx >> 5) * 4;   // 0..28  (32 rows)
  float acc[4][4] = {};
  #pragma unroll 4
  for (int k = 0; k < K; ++k) {
    f4 wv = *(const f4*)&wt[k*128 + c0];
    float x0 = xs[(r0+0)*K + k];
    float x1 = xs[(r0+1)*K + k];
    float x2 = xs[(r0+2)*K + k];
    float x3 = xs[(r0+3)*K + k];
    acc[0][0] = fmaf(x0, wv.x, acc[0][0]); acc[0][1] = fmaf(x0, wv.y, acc[0][1]);
    acc[0][2] = fmaf(x0, wv.z, acc[0][2]); acc[0][3] = fmaf(x0, wv.w, acc[0][3]);
    acc[1][0] = fmaf(x1, wv.x, acc[1][0]); acc[1][1] = fmaf(x1, wv.y, acc[1][1]);
    acc[1][2] = fmaf(x1, wv.z, acc[1][2]); acc[1][3] = fmaf(x1, wv.w, acc[1][3]);
    acc[2][0] = fmaf(x2, wv.x, acc[2][0]); acc[2][1] = fmaf(x2, wv.y, acc[2][1]);
    acc[2][2] = fmaf(x2, wv.z, acc[2][2]); acc[2][3] = fmaf(x2, wv.w, acc[2][3]);
    acc[3][0] = fmaf(x3, wv.x, acc[3][0]); acc[3][1] = fmaf(x3, wv.y, acc[3][1]);
    acc[3][2] = fmaf(x3, wv.z, acc[3][2]); acc[3][3] = fmaf(x3, wv.w, acc[3][3]);
  }
  const bool second = (c0 >= 64);
  const int cc = second ? (c0 - 64) : c0;
  f4 bv = {0.f,0.f,0.f,0.f};
  if (second) bv = *(const f4*)&bias2[cc];
  float* __restrict__ outp = second ? out2 : out1;
  #pragma unroll
  for (int r = 0; r < 4; ++r) {
    int grow = row0 + r0 + r;
    if (grow < N_NODES) {
      f4 o;
      o.x = acc[r][0] + bv.x; o.y = acc[r][1] + bv.y;
      o.z = acc[r][2] + bv.z; o.w = acc[r][3] + bv.w;
      *(f4*)&outp[grow*64 + cc] = o;
    }
  }
}

// ------------- final dual GEMM (K=192 via 2 chunks of 96, 80 out channels) -------------
__global__ __launch_bounds__(320) void k_gemm_final(
    const float* __restrict__ hpre, const float* __restrict__ ss,
    const float* __restrict__ af, const float* __restrict__ wtg,
    const float* __restrict__ bc,
    float* __restrict__ yl, float* __restrict__ yr) {
  __shared__ float wt[96*80];
  __shared__ float xs[64*100];
  const int tx = threadIdx.x;
  const int row0 = blockIdx.x * 64;
  const int c0 = (tx % 20) * 4;   // 0..76 (80 channels)
  const int r0 = (tx / 20) * 4;   // 0..60 (64 rows)
  float acc[4][4] = {};
  for (int chunk = 0; chunk < 2; ++chunk) {
    if (chunk) __syncthreads();
    for (int i = tx; i < 96*20; i += 320) ((f4*)wt)[i] = ((const f4*)(wtg + chunk*96*80))[i];
    for (int i = tx; i < 64*24; i += 320) {
      int row = i / 24, p = i % 24;
      int kg = chunk*96 + p*4;
      int grow = row0 + row;
      f4 v = {0.f,0.f,0.f,0.f};
      if (grow < N_NODES) {
        if (kg < 64) {
          v = *(const f4*)&hpre[grow*64 + kg];
          v.x = fmaxf(0.f, fmaf(v.x, ss[kg+0], ss[64+kg+0]));
          v.y = fmaxf(0.f, fmaf(v.y, ss[kg+1], ss[64+kg+1]));
          v.z = fmaxf(0.f, fmaf(v.z, ss[kg+2], ss[64+kg+2]));
          v.w = fmaxf(0.f, fmaf(v.w, ss[kg+3], ss[64+kg+3]));
        } else {
          v = *(const f4*)&af[grow*128 + kg - 64];
        }
      }
      *(f4*)&xs[row*100 + p*4] = v;
    }
    __syncthreads();
    #pragma unroll 4
    for (int kk = 0; kk < 96; ++kk) {
      f4 wv = *(const f4*)&wt[kk*80 + c0];
      float x0 = xs[(r0+0)*100 + kk];
      float x1 = xs[(r0+1)*100 + kk];
      float x2 = xs[(r0+2)*100 + kk];
      float x3 = xs[(r0+3)*100 + kk];
      acc[0][0] = fmaf(x0, wv.x, acc[0][0]); acc[0][1] = fmaf(x0, wv.y, acc[0][1]);
      acc[0][2] = fmaf(x0, wv.z, acc[0][2]); acc[0][3] = fmaf(x0, wv.w, acc[0][3]);
      acc[1][0] = fmaf(x1, wv.x, acc[1][0]); acc[1][1] = fmaf(x1, wv.y, acc[1][1]);
      acc[1][2] = fmaf(x1, wv.z, acc[1][2]); acc[1][3] = fmaf(x1, wv.w, acc[1][3]);
      acc[2][0] = fmaf(x2, wv.x, acc[2][0]); acc[2][1] = fmaf(x2, wv.y, acc[2][1]);
      acc[2][2] = fmaf(x2, wv.z, acc[2][2]); acc[2][3] = fmaf(x2, wv.w, acc[2][3]);
      acc[3][0] = fmaf(x3, wv.x, acc[3][0]); acc[3][1] = fmaf(x3, wv.y, acc[3][1]);
      acc[3][2] = fmaf(x3, wv.z, acc[3][2]); acc[3][3] = fmaf(x3, wv.w, acc[3][3]);
    }
  }
  const bool second = (c0 >= 40);
  const int cc = second ? (c0 - 40) : c0;
  f4 bv = *(const f4*)&bc[second ? 40 + cc : cc];
  float* __restrict__ outp = second ? yr : yl;
  #pragma unroll
  for (int r = 0; r < 4; ++r) {
    int grow = row0 + r0 + r;
    if (grow < N_NODES) {
      f4 o;
      o.x = acc[r][0] + bv.x; o.y = acc[r][1] + bv.y;
      o.z = acc[r][2] + bv.z; o.w = acc[r][3] + bv.w;
      *(f4*)&outp[grow*40 + cc] = o;
    }
  }
}

// ------------- edge scatter (atomic) -------------
__global__ __launch_bounds__(256) void k_scatter64(const int* __restrict__ src, const int* __restrict__ dst,
                                                   const float* __restrict__ y, float* __restrict__ agg) {
  int t = blockIdx.x * 256 + threadIdx.x;
  int e = t >> 4;
  if (e >= N_EDGES) return;
  int c = (t & 15) * 4;
  int s = src[e], d = dst[e];
  f4 v = *(const f4*)&y[s*64 + c];
  float* p = &agg[d*64 + c];
  atomicAdd(p+0, v.x); atomicAdd(p+1, v.y); atomicAdd(p+2, v.z); atomicAdd(p+3, v.w);
}

__global__ __launch_bounds__(256) void k_scatter40(const int* __restrict__ src, const int* __restrict__ dst,
                                                   const float* __restrict__ y, float* __restrict__ agg) {
  int t = blockIdx.x * 256 + threadIdx.x;
  int e = t / 10;
  if (e >= N_EDGES) return;
  int c = (t - e*10) * 4;
  int s = src[e], d = dst[e];
  f4 v = *(const f4*)&y[s*40 + c];
  float* p = &agg[d*40 + c];
  atomicAdd(p+0, v.x); atomicAdd(p+1, v.y); atomicAdd(p+2, v.z); atomicAdd(p+3, v.w);
}

// ------------- h_pre = agg*invdeg + yr ; accumulate BN stats -------------
__global__ __launch_bounds__(256) void k_finalize(const float* __restrict__ agg, const float* __restrict__ yr,
                                                  const float* __restrict__ invd, float* __restrict__ hpre,
                                                  float* __restrict__ stats) {
  __shared__ float ssum[64], ssq[64];
  int t = threadIdx.x;
  if (t < 64) { ssum[t] = 0.f; ssq[t] = 0.f; }
  __syncthreads();
  int idx = (blockIdx.x * 256 + t) * 4;
  if (idx < N_NODES*64) {
    int row = idx >> 6;
    int c0 = idx & 63;
    float inv = invd[row];
    f4 a = *(const f4*)&agg[idx];
    f4 y = *(const f4*)&yr[idx];
    f4 h;
    h.x = fmaf(a.x, inv, y.x); h.y = fmaf(a.y, inv, y.y);
    h.z = fmaf(a.z, inv, y.z); h.w = fmaf(a.w, inv, y.w);
    *(f4*)&hpre[idx] = h;
    atomicAdd(&ssum[c0+0], h.x); atomicAdd(&ssq[c0+0], h.x*h.x);
    atomicAdd(&ssum[c0+1], h.y); atomicAdd(&ssq[c0+1], h.y*h.y);
    atomicAdd(&ssum[c0+2], h.z); atomicAdd(&ssq[c0+2], h.z*h.z);
    atomicAdd(&ssum[c0+3], h.w); atomicAdd(&ssq[c0+3], h.w*h.w);
  }
  __syncthreads();
  if (t < 64) { atomicAdd(&stats[t], ssum[t]); atomicAdd(&stats[64+t], ssq[t]); }
}

__global__ void k_bnparams(const float* __restrict__ stats, const float* __restrict__ g,
                           const float* __restrict__ be, float* __restrict__ ss) {
  int c = threadIdx.x; // 64
  float mean = stats[c] * (1.0f / N_NODES);
  float var  = stats[64+c] * (1.0f / N_NODES) - mean*mean;
  float scale = g[c] * rsqrtf(var + 1e-5f);
  ss[c] = scale;
  ss[64+c] = be[c] - mean*scale;
}

// ------------- out = log_softmax(agg*invdeg + yr) -------------
__global__ __launch_bounds__(256) void k_out(const float* __restrict__ agg, const float* __restrict__ yr,
                                             const float* __restrict__ invd, float* __restrict__ out) {
  int row = blockIdx.x * 4 + (threadIdx.x >> 6);
  int lane = threadIdx.x & 63;
  if (row >= N_NODES) return;
  float v = -1e30f;
  float inv = invd[row];
  if (lane < 40) v = fmaf(agg[row*40 + lane], inv, yr[row*40 + lane]);
  float m = v;
  #pragma unroll
  for (int off = 32; off >= 1; off >>= 1) m = fmaxf(m, __shfl_xor(m, off, 64));
  float e = (lane < 40) ? __expf(v - m) : 0.f;
  float s = e;
  #pragma unroll
  for (int off = 32; off >= 1; off >>= 1) s += __shfl_xor(s, off, 64);
  if (lane < 40) out[row*40 + lane] = v - m - __logf(s);
}

extern "C" void kernel_launch(void* const* d_in, const int* in_sizes, int n_in,
                              void* d_out, int out_size, void* d_ws, size_t ws_size,
                              hipStream_t stream) {
  const float* x   = (const float*)d_in[0];
  const int*   esrc = (const int*)d_in[1];
  const int*   edst = (const int*)d_in[2];
  const float* af  = (const float*)d_in[3];
  const float* Wl0 = (const float*)d_in[4];
  const float* Wr0 = (const float*)d_in[5];
  const float* b0  = (const float*)d_in[6];
  const float* g0  = (const float*)d_in[7];
  const float* be0 = (const float*)d_in[8];
  const float* Wl1 = (const float*)d_in[9];
  const float* Wr1 = (const float*)d_in[10];
  const float* b1  = (const float*)d_in[11];
  const float* g1  = (const float*)d_in[12];
  const float* be1 = (const float*)d_in[13];
  const float* Wf  = (const float*)d_in[14];
  const float* bfv = (const float*)d_in[15];
  const float* Wl2 = (const float*)d_in[16];
  const float* Wr2 = (const float*)d_in[17];
  const float* b2  = (const float*)d_in[18];

  float* ws   = (float*)d_ws;
  float* invd = ws;                          // N
  float* bufA = ws + (size_t)100000;         // N*64  (yl stage; yl2 uses first N*40)
  float* bufB = ws + (size_t)6500000;        // N*64  (agg / h_pre; agg2 uses first N*40)
  float* bufC = ws + (size_t)12900000;       // N*64  (yr stage; yr2 uses first N*40)
  float* stats = ws + (size_t)19300000;      // 512: [s0 sum|sq][ss0 scale|shift][s1][ss1]
  float* Wcl  = stats + 512;                 // 40*128
  float* Wcr  = Wcl + 5120;                  // 40*128
  float* bc   = Wcr + 5120;                  // 80
  float* WT0  = bc + 80;                     // 128*128
  float* WT1  = WT0 + 16384;                 // 64*128
  float* WTF  = WT1 + 8192;                  // 192*80
  float* out  = (float*)d_out;

  hipMemsetAsync(invd, 0, 100000*sizeof(float), stream);
  hipMemsetAsync(stats, 0, 512*sizeof(float), stream);
  k_deg<<<6250, 256, 0, stream>>>(edst, invd);
  k_invdeg<<<391, 256, 0, stream>>>(invd);
  k_precomp<<<40, 128, 0, stream>>>(Wl2, Wr2, Wf, bfv, b2, Wcl, Wcr, bc);
  k_buildwt<128><<<64, 256, 0, stream>>>(Wl0, Wr0, WT0);
  k_buildwt<64><<<32, 256, 0, stream>>>(Wl1, Wr1, WT1);
  k_buildwtf<<<60, 256, 0, stream>>>(Wl2, Wr2, Wcl, Wcr, WTF);

  // ---- layer 0 ----
  k_gemm_dual<128,false><<<3125, 256, 0, stream>>>(x, nullptr, WT0, b0, bufA, bufC);
  hipMemsetAsync(bufB, 0, (size_t)6400000*sizeof(float), stream);
  k_scatter64<<<100000, 256, 0, stream>>>(esrc, edst, bufA, bufB);
  k_finalize<<<6250, 256, 0, stream>>>(bufB, bufC, invd, bufB, stats);
  k_bnparams<<<1, 64, 0, stream>>>(stats, g0, be0, stats + 128);

  // ---- layer 1 ----
  k_gemm_dual<64,true><<<3125, 256, 0, stream>>>(bufB, stats + 128, WT1, b1, bufA, bufC);
  hipMemsetAsync(bufB, 0, (size_t)6400000*sizeof(float), stream);
  k_scatter64<<<100000, 256, 0, stream>>>(esrc, edst, bufA, bufB);
  k_finalize<<<6250, 256, 0, stream>>>(bufB, bufC, invd, bufB, stats + 256);
  k_bnparams<<<1, 64, 0, stream>>>(stats + 256, g1, be1, stats + 384);

  // ---- final layer (concat folded via precomputed combined weights) ----
  k_gemm_final<<<1563, 320, 0, stream>>>(bufB, stats + 384, af, WTF, bc, bufA, bufC);
  hipMemsetAsync(bufB, 0, (size_t)4000000*sizeof(float), stream);
  k_scatter40<<<62500, 256, 0, stream>>>(esrc, edst, bufA, bufB);
  k_out<<<25000, 256, 0, stream>>>(bufB, bufC, invd, out);
}

// Round 2
// 1346.477 us; speedup vs baseline: 3.1665x; 3.1665x over previous
//
#include <hip/hip_runtime.h>

#define N_NODES 100000
#define N_EDGES 1600000

typedef float4 f4;

// ---------------- CSR build ----------------
__global__ __launch_bounds__(256) void k_count(const int* __restrict__ dst, int* __restrict__ counts) {
  int i = blockIdx.x * 256 + threadIdx.x;
  if (i < N_EDGES) atomicAdd(&counts[dst[i]], 1);
}

// single block, 1024 threads: exclusive scan of counts -> rowptr, cursor; invd = 1/max(deg,1)
__global__ __launch_bounds__(1024) void k_scan(const int* __restrict__ counts, int* __restrict__ rowptr,
                                               int* __restrict__ cursor, float* __restrict__ invd) {
  __shared__ int part[1024];
  const int t = threadIdx.x;
  const int CH = (N_NODES + 1023) / 1024;  // 98
  const int base = t * CH;
  int s = 0;
  for (int i = 0; i < CH; ++i) { int idx = base + i; if (idx < N_NODES) s += counts[idx]; }
  part[t] = s; __syncthreads();
  for (int off = 1; off < 1024; off <<= 1) {
    int v = (t >= off) ? part[t - off] : 0;
    __syncthreads();
    part[t] += v;
    __syncthreads();
  }
  int run = part[t] - s;  // exclusive prefix
  for (int i = 0; i < CH; ++i) {
    int idx = base + i;
    if (idx < N_NODES) {
      int c = counts[idx];
      rowptr[idx] = run;
      invd[idx] = 1.0f / fmaxf((float)c, 1.0f);
      cursor[idx] = run;   // cursor may alias counts: c already read
      run += c;
    }
  }
  if (t == 1023) rowptr[N_NODES] = part[1023];
}

__global__ __launch_bounds__(256) void k_place(const int* __restrict__ src, const int* __restrict__ dst,
                                               int* __restrict__ cursor, int* __restrict__ srcs) {
  int e = blockIdx.x * 256 + threadIdx.x;
  if (e < N_EDGES) {
    int pos = atomicAdd(&cursor[dst[e]], 1);
    srcs[pos] = src[e];
  }
}

// ------------- combined projection weights for final layer -------------
__global__ void k_precomp(const float* __restrict__ Wl2, const float* __restrict__ Wr2,
                          const float* __restrict__ Wf, const float* __restrict__ bfv,
                          const float* __restrict__ b2,
                          float* __restrict__ Wcl, float* __restrict__ Wcr, float* __restrict__ bc) {
  int o = blockIdx.x, k = threadIdx.x;  // o<40, k<128
  float al = 0.f, ar = 0.f;
  for (int j = 0; j < 64; ++j) {
    float wl = Wl2[o*128 + 64 + j], wr = Wr2[o*128 + 64 + j];
    float wf = Wf[j*128 + k];
    al = fmaf(wl, wf, al); ar = fmaf(wr, wf, ar);
  }
  Wcl[o*128 + k] = al; Wcr[o*128 + k] = ar;
  if (k == 0) {
    float sl = 0.f, sr = 0.f;
    for (int j = 0; j < 64; ++j) { sl += Wl2[o*128+64+j]*bfv[j]; sr += Wr2[o*128+64+j]*bfv[j]; }
    bc[o] = sl; bc[40+o] = sr + b2[o];
  }
}

template<int K>
__global__ __launch_bounds__(256) void k_buildwt(const float* __restrict__ W1, const float* __restrict__ W2,
                                                 float* __restrict__ dst) {
  int idx = blockIdx.x * 256 + threadIdx.x;
  if (idx >= K*128) return;
  int c = idx & 127, k = idx >> 7;
  dst[idx] = (c < 64) ? W1[c*K + k] : W2[(c-64)*K + k];
}

__global__ __launch_bounds__(256) void k_buildwtf(const float* __restrict__ Wl2, const float* __restrict__ Wr2,
                                                  const float* __restrict__ Wcl, const float* __restrict__ Wcr,
                                                  float* __restrict__ dst) {
  int idx = blockIdx.x * 256 + threadIdx.x;
  if (idx >= 192*80) return;
  int c = idx % 80, k = idx / 80;
  float w;
  if (k < 64) w = (c < 40) ? Wl2[c*128 + k] : Wr2[(c-40)*128 + k];
  else        w = (c < 40) ? Wcl[c*128 + k-64] : Wcr[(c-40)*128 + k-64];
  dst[idx] = w;
}

// ------------- dual GEMM: out1 = in@W1.T, out2 = in@W2.T + bias2 -------------
template<int K, bool BN>
__global__ __launch_bounds__(256) void k_gemm_dual(
    const float* __restrict__ in, const float* __restrict__ ss,
    const float* __restrict__ wtg, const float* __restrict__ bias2,
    float* __restrict__ out1, float* __restrict__ out2) {
  __shared__ float wt[K*128];
  __shared__ float xs[32*K];
  const int tx = threadIdx.x;
  for (int i = tx; i < K*32; i += 256) ((f4*)wt)[i] = ((const f4*)wtg)[i];
  const int row0 = blockIdx.x * 32;
  for (int i = tx; i < 32*(K/4); i += 256) {
    int row = i / (K/4), kq = i % (K/4);
    int grow = row0 + row;
    f4 v = {0.f,0.f,0.f,0.f};
    if (grow < N_NODES) {
      v = *(const f4*)&in[grow*K + kq*4];
      if (BN) {
        int c = kq*4;
        v.x = fmaxf(0.f, fmaf(v.x, ss[c+0], ss[K+c+0]));
        v.y = fmaxf(0.f, fmaf(v.y, ss[c+1], ss[K+c+1]));
        v.z = fmaxf(0.f, fmaf(v.z, ss[c+2], ss[K+c+2]));
        v.w = fmaxf(0.f, fmaf(v.w, ss[c+3], ss[K+c+3]));
      }
    }
    *(f4*)&xs[row*K + kq*4] = v;
  }
  __syncthreads();
  const int c0 = (tx & 31) * 4;
  const int r0 = (tx >> 5) * 4;
  float acc[4][4] = {};
  #pragma unroll 4
  for (int k = 0; k < K; ++k) {
    f4 wv = *(const f4*)&wt[k*128 + c0];
    float x0 = xs[(r0+0)*K + k];
    float x1 = xs[(r0+1)*K + k];
    float x2 = xs[(r0+2)*K + k];
    float x3 = xs[(r0+3)*K + k];
    acc[0][0] = fmaf(x0, wv.x, acc[0][0]); acc[0][1] = fmaf(x0, wv.y, acc[0][1]);
    acc[0][2] = fmaf(x0, wv.z, acc[0][2]); acc[0][3] = fmaf(x0, wv.w, acc[0][3]);
    acc[1][0] = fmaf(x1, wv.x, acc[1][0]); acc[1][1] = fmaf(x1, wv.y, acc[1][1]);
    acc[1][2] = fmaf(x1, wv.z, acc[1][2]); acc[1][3] = fmaf(x1, wv.w, acc[1][3]);
    acc[2][0] = fmaf(x2, wv.x, acc[2][0]); acc[2][1] = fmaf(x2, wv.y, acc[2][1]);
    acc[2][2] = fmaf(x2, wv.z, acc[2][2]); acc[2][3] = fmaf(x2, wv.w, acc[2][3]);
    acc[3][0] = fmaf(x3, wv.x, acc[3][0]); acc[3][1] = fmaf(x3, wv.y, acc[3][1]);
    acc[3][2] = fmaf(x3, wv.z, acc[3][2]); acc[3][3] = fmaf(x3, wv.w, acc[3][3]);
  }
  const bool second = (c0 >= 64);
  const int cc = second ? (c0 - 64) : c0;
  f4 bv = {0.f,0.f,0.f,0.f};
  if (second) bv = *(const f4*)&bias2[cc];
  float* __restrict__ outp = second ? out2 : out1;
  #pragma unroll
  for (int r = 0; r < 4; ++r) {
    int grow = row0 + r0 + r;
    if (grow < N_NODES) {
      f4 o;
      o.x = acc[r][0] + bv.x; o.y = acc[r][1] + bv.y;
      o.z = acc[r][2] + bv.z; o.w = acc[r][3] + bv.w;
      *(f4*)&outp[grow*64 + cc] = o;
    }
  }
}

// ------------- final dual GEMM (K=192 via 2 chunks of 96, 80 out channels) -------------
__global__ __launch_bounds__(320) void k_gemm_final(
    const float* __restrict__ hpre, const float* __restrict__ ss,
    const float* __restrict__ af, const float* __restrict__ wtg,
    const float* __restrict__ bc,
    float* __restrict__ yl, float* __restrict__ yr) {
  __shared__ float wt[96*80];
  __shared__ float xs[64*100];
  const int tx = threadIdx.x;
  const int row0 = blockIdx.x * 64;
  const int c0 = (tx % 20) * 4;
  const int r0 = (tx / 20) * 4;
  float acc[4][4] = {};
  for (int chunk = 0; chunk < 2; ++chunk) {
    if (chunk) __syncthreads();
    for (int i = tx; i < 96*20; i += 320) ((f4*)wt)[i] = ((const f4*)(wtg + chunk*96*80))[i];
    for (int i = tx; i < 64*24; i += 320) {
      int row = i / 24, p = i % 24;
      int kg = chunk*96 + p*4;
      int grow = row0 + row;
      f4 v = {0.f,0.f,0.f,0.f};
      if (grow < N_NODES) {
        if (kg < 64) {
          v = *(const f4*)&hpre[grow*64 + kg];
          v.x = fmaxf(0.f, fmaf(v.x, ss[kg+0], ss[64+kg+0]));
          v.y = fmaxf(0.f, fmaf(v.y, ss[kg+1], ss[64+kg+1]));
          v.z = fmaxf(0.f, fmaf(v.z, ss[kg+2], ss[64+kg+2]));
          v.w = fmaxf(0.f, fmaf(v.w, ss[kg+3], ss[64+kg+3]));
        } else {
          v = *(const f4*)&af[grow*128 + kg - 64];
        }
      }
      *(f4*)&xs[row*100 + p*4] = v;
    }
    __syncthreads();
    #pragma unroll 4
    for (int kk = 0; kk < 96; ++kk) {
      f4 wv = *(const f4*)&wt[kk*80 + c0];
      float x0 = xs[(r0+0)*100 + kk];
      float x1 = xs[(r0+1)*100 + kk];
      float x2 = xs[(r0+2)*100 + kk];
      float x3 = xs[(r0+3)*100 + kk];
      acc[0][0] = fmaf(x0, wv.x, acc[0][0]); acc[0][1] = fmaf(x0, wv.y, acc[0][1]);
      acc[0][2] = fmaf(x0, wv.z, acc[0][2]); acc[0][3] = fmaf(x0, wv.w, acc[0][3]);
      acc[1][0] = fmaf(x1, wv.x, acc[1][0]); acc[1][1] = fmaf(x1, wv.y, acc[1][1]);
      acc[1][2] = fmaf(x1, wv.z, acc[1][2]); acc[1][3] = fmaf(x1, wv.w, acc[1][3]);
      acc[2][0] = fmaf(x2, wv.x, acc[2][0]); acc[2][1] = fmaf(x2, wv.y, acc[2][1]);
      acc[2][2] = fmaf(x2, wv.z, acc[2][2]); acc[2][3] = fmaf(x2, wv.w, acc[2][3]);
      acc[3][0] = fmaf(x3, wv.x, acc[3][0]); acc[3][1] = fmaf(x3, wv.y, acc[3][1]);
      acc[3][2] = fmaf(x3, wv.z, acc[3][2]); acc[3][3] = fmaf(x3, wv.w, acc[3][3]);
    }
  }
  const bool second = (c0 >= 40);
  const int cc = second ? (c0 - 40) : c0;
  f4 bv = *(const f4*)&bc[second ? 40 + cc : cc];
  float* __restrict__ outp = second ? yr : yl;
  #pragma unroll
  for (int r = 0; r < 4; ++r) {
    int grow = row0 + r0 + r;
    if (grow < N_NODES) {
      f4 o;
      o.x = acc[r][0] + bv.x; o.y = acc[r][1] + bv.y;
      o.z = acc[r][2] + bv.z; o.w = acc[r][3] + bv.w;
      *(f4*)&outp[grow*40 + cc] = o;
    }
  }
}

// ------------- CSR gather + finalize (+BN stats) -------------
// one wave per 4 nodes; lane c accumulates channel c over incoming edges
template<bool STATS>
__global__ __launch_bounds__(256) void k_gather64(
    const int* __restrict__ rowptr, const int* __restrict__ srcs,
    const float* __restrict__ y, const float* __restrict__ yr,
    const float* __restrict__ invd, float* __restrict__ hpre, float* __restrict__ stats) {
  __shared__ float ssum[64], ssq[64];
  const int t = threadIdx.x;
  const int lane = t & 63, w = t >> 6;
  if (STATS) { if (t < 64) { ssum[t] = 0.f; ssq[t] = 0.f; } __syncthreads(); }
  const int node0 = blockIdx.x * 16 + w * 4;
  float psum = 0.f, psq = 0.f;
  #pragma unroll
  for (int n = 0; n < 4; ++n) {
    const int node = node0 + n;
    const int beg = rowptr[node], end = rowptr[node + 1];
    float acc = 0.f;
    for (int e = beg; e < end; ++e) {
      int s = srcs[e];
      acc += y[s * 64 + lane];
    }
    float h = fmaf(acc, invd[node], yr[node * 64 + lane]);
    hpre[node * 64 + lane] = h;
    if (STATS) { psum += h; psq += h * h; }
  }
  if (STATS) {
    atomicAdd(&ssum[lane], psum); atomicAdd(&ssq[lane], psq);
    __syncthreads();
    if (t < 64) { atomicAdd(&stats[t], ssum[t]); atomicAdd(&stats[64 + t], ssq[t]); }
  }
}

__global__ void k_bnparams(const float* __restrict__ stats, const float* __restrict__ g,
                           const float* __restrict__ be, float* __restrict__ ss) {
  int c = threadIdx.x; // 64
  float mean = stats[c] * (1.0f / N_NODES);
  float var  = stats[64+c] * (1.0f / N_NODES) - mean*mean;
  float scale = g[c] * rsqrtf(var + 1e-5f);
  ss[c] = scale;
  ss[64+c] = be[c] - mean*scale;
}

// ------------- CSR gather (40ch) + log_softmax fused -------------
__global__ __launch_bounds__(256) void k_gather_out(
    const int* __restrict__ rowptr, const int* __restrict__ srcs,
    const float* __restrict__ y, const float* __restrict__ yr,
    const float* __restrict__ invd, float* __restrict__ out) {
  const int t = threadIdx.x;
  const int lane = t & 63, w = t >> 6;
  const int node0 = blockIdx.x * 16 + w * 4;
  #pragma unroll
  for (int n = 0; n < 4; ++n) {
    const int node = node0 + n;
    const int beg = rowptr[node], end = rowptr[node + 1];
    float acc = 0.f;
    if (lane < 40) {
      for (int e = beg; e < end; ++e) {
        int s = srcs[e];
        acc += y[s * 40 + lane];
      }
    }
    float v = (lane < 40) ? fmaf(acc, invd[node], yr[node * 40 + lane]) : -1e30f;
    float m = v;
    #pragma unroll
    for (int off = 32; off >= 1; off >>= 1) m = fmaxf(m, __shfl_xor(m, off, 64));
    float e_ = (lane < 40) ? __expf(v - m) : 0.f;
    float s_ = e_;
    #pragma unroll
    for (int off = 32; off >= 1; off >>= 1) s_ += __shfl_xor(s_, off, 64);
    if (lane < 40) out[node * 40 + lane] = v - m - __logf(s_);
  }
}

extern "C" void kernel_launch(void* const* d_in, const int* in_sizes, int n_in,
                              void* d_out, int out_size, void* d_ws, size_t ws_size,
                              hipStream_t stream) {
  const float* x   = (const float*)d_in[0];
  const int*   esrc = (const int*)d_in[1];
  const int*   edst = (const int*)d_in[2];
  const float* af  = (const float*)d_in[3];
  const float* Wl0 = (const float*)d_in[4];
  const float* Wr0 = (const float*)d_in[5];
  const float* b0  = (const float*)d_in[6];
  const float* g0  = (const float*)d_in[7];
  const float* be0 = (const float*)d_in[8];
  const float* Wl1 = (const float*)d_in[9];
  const float* Wr1 = (const float*)d_in[10];
  const float* b1  = (const float*)d_in[11];
  const float* g1  = (const float*)d_in[12];
  const float* be1 = (const float*)d_in[13];
  const float* Wf  = (const float*)d_in[14];
  const float* bfv = (const float*)d_in[15];
  const float* Wl2 = (const float*)d_in[16];
  const float* Wr2 = (const float*)d_in[17];
  const float* b2  = (const float*)d_in[18];

  float* ws   = (float*)d_ws;
  float* invd = ws;                          // N
  float* bufA = ws + (size_t)100000;         // N*64 (y stage)
  float* bufB = bufA + (size_t)6400000;      // N*64 (h_pre)
  float* bufC = bufB + (size_t)6400000;      // N*64 (yr stage)
  float* stats = bufC + (size_t)6400000;     // 512
  float* Wcl  = stats + 512;                 // 40*128
  float* Wcr  = Wcl + 5120;                  // 40*128
  float* bc   = Wcr + 5120;                  // 80
  float* WT0  = bc + 80;                     // 128*128
  float* WT1  = WT0 + 16384;                 // 64*128
  float* WTF  = WT1 + 8192;                  // 192*80
  int*   counts = (int*)(WTF + 15360);       // N (aliased as cursor)
  int*   rowptr = counts + 100000;           // N+1
  int*   srcs   = rowptr + 100001;           // E
  float* out  = (float*)d_out;

  // ---- CSR build (reused by all 3 layers) ----
  hipMemsetAsync(counts, 0, 100000*sizeof(int), stream);
  hipMemsetAsync(stats, 0, 512*sizeof(float), stream);
  k_count<<<6250, 256, 0, stream>>>(edst, counts);
  k_scan<<<1, 1024, 0, stream>>>(counts, rowptr, counts /*cursor alias*/, invd);
  k_place<<<6250, 256, 0, stream>>>(esrc, edst, counts, srcs);

  k_precomp<<<40, 128, 0, stream>>>(Wl2, Wr2, Wf, bfv, b2, Wcl, Wcr, bc);
  k_buildwt<128><<<64, 256, 0, stream>>>(Wl0, Wr0, WT0);
  k_buildwt<64><<<32, 256, 0, stream>>>(Wl1, Wr1, WT1);
  k_buildwtf<<<60, 256, 0, stream>>>(Wl2, Wr2, Wcl, Wcr, WTF);

  // ---- layer 0 ----
  k_gemm_dual<128,false><<<3125, 256, 0, stream>>>(x, nullptr, WT0, b0, bufA, bufC);
  k_gather64<true><<<6250, 256, 0, stream>>>(rowptr, srcs, bufA, bufC, invd, bufB, stats);
  k_bnparams<<<1, 64, 0, stream>>>(stats, g0, be0, stats + 128);

  // ---- layer 1 ----
  k_gemm_dual<64,true><<<3125, 256, 0, stream>>>(bufB, stats + 128, WT1, b1, bufA, bufC);
  k_gather64<true><<<6250, 256, 0, stream>>>(rowptr, srcs, bufA, bufC, invd, bufB, stats + 256);
  k_bnparams<<<1, 64, 0, stream>>>(stats + 256, g1, be1, stats + 384);

  // ---- final layer (concat folded via precomputed combined weights) ----
  k_gemm_final<<<1563, 320, 0, stream>>>(bufB, stats + 384, af, WTF, bc, bufA, bufC);
  k_gather_out<<<6250, 256, 0, stream>>>(rowptr, srcs, bufA, bufC, invd, out);
}

// Round 3
// 1044.868 us; speedup vs baseline: 4.0805x; 1.2887x over previous
//
#include <hip/hip_runtime.h>

#define N_NODES 100000
#define N_EDGES 1600000
#define SCAN_NBLK 98   // ceil(100000/1024)

typedef float4 f4;

// ---------------- CSR build ----------------
__global__ __launch_bounds__(256) void k_count(const int* __restrict__ dst, int* __restrict__ counts) {
  int i = blockIdx.x * 256 + threadIdx.x;
  if (i < N_EDGES) atomicAdd(&counts[dst[i]], 1);
}

// phase A: per-block (1024 elems) reduce
__global__ __launch_bounds__(256) void k_scan_a(const int* __restrict__ counts, int* __restrict__ blk) {
  __shared__ int red[256];
  const int t = threadIdx.x;
  const int base = blockIdx.x * 1024;
  int s = 0;
  #pragma unroll
  for (int i = 0; i < 4; ++i) {
    int idx = base + t + i * 256;
    if (idx < N_NODES) s += counts[idx];
  }
  red[t] = s; __syncthreads();
  for (int off = 128; off >= 1; off >>= 1) {
    if (t < off) red[t] += red[t + off];
    __syncthreads();
  }
  if (t == 0) blk[blockIdx.x] = red[0];
}

// phase B: single block exclusive scan of SCAN_NBLK block sums
__global__ __launch_bounds__(128) void k_scan_b(int* __restrict__ blk) {
  __shared__ int v[128];
  const int t = threadIdx.x;
  int val = (t < SCAN_NBLK) ? blk[t] : 0;
  v[t] = val; __syncthreads();
  for (int off = 1; off < 128; off <<= 1) {
    int a = (t >= off) ? v[t - off] : 0;
    __syncthreads();
    v[t] += a;
    __syncthreads();
  }
  if (t < SCAN_NBLK) blk[t] = v[t] - val;  // exclusive
}

// phase C: per-block scan + offset -> rowptr, cursor, invd
__global__ __launch_bounds__(256) void k_scan_c(const int* __restrict__ counts, const int* __restrict__ blkoff,
                                                int* __restrict__ rowptr, int* __restrict__ cursor,
                                                float* __restrict__ invd) {
  __shared__ int ps[256];
  const int t = threadIdx.x;
  const int base = blockIdx.x * 1024 + t * 4;
  int c[4]; int s = 0;
  #pragma unroll
  for (int i = 0; i < 4; ++i) {
    int idx = base + i;
    c[i] = (idx < N_NODES) ? counts[idx] : 0;
    s += c[i];
  }
  ps[t] = s; __syncthreads();
  for (int off = 1; off < 256; off <<= 1) {
    int a = (t >= off) ? ps[t - off] : 0;
    __syncthreads();
    ps[t] += a;
    __syncthreads();
  }
  int run = blkoff[blockIdx.x] + ps[t] - s;
  #pragma unroll
  for (int i = 0; i < 4; ++i) {
    int idx = base + i;
    if (idx < N_NODES) {
      rowptr[idx] = run;
      cursor[idx] = run;          // cursor may alias counts: c[] already read
      invd[idx] = 1.0f / fmaxf((float)c[i], 1.0f);
      run += c[i];
      if (idx == N_NODES - 1) rowptr[N_NODES] = run;
    }
  }
}

__global__ __launch_bounds__(256) void k_place(const int* __restrict__ src, const int* __restrict__ dst,
                                               int* __restrict__ cursor, int* __restrict__ srcs) {
  int e = blockIdx.x * 256 + threadIdx.x;
  if (e < N_EDGES) {
    int pos = atomicAdd(&cursor[dst[e]], 1);
    srcs[pos] = src[e];
  }
}

// ------------- combined projection weights for final layer -------------
__global__ void k_precomp(const float* __restrict__ Wl2, const float* __restrict__ Wr2,
                          const float* __restrict__ Wf, const float* __restrict__ bfv,
                          const float* __restrict__ b2,
                          float* __restrict__ Wcl, float* __restrict__ Wcr, float* __restrict__ bc) {
  int o = blockIdx.x, k = threadIdx.x;  // o<40, k<128
  float al = 0.f, ar = 0.f;
  for (int j = 0; j < 64; ++j) {
    float wl = Wl2[o*128 + 64 + j], wr = Wr2[o*128 + 64 + j];
    float wf = Wf[j*128 + k];
    al = fmaf(wl, wf, al); ar = fmaf(wr, wf, ar);
  }
  Wcl[o*128 + k] = al; Wcr[o*128 + k] = ar;
  if (k == 0) {
    float sl = 0.f, sr = 0.f;
    for (int j = 0; j < 64; ++j) { sl += Wl2[o*128+64+j]*bfv[j]; sr += Wr2[o*128+64+j]*bfv[j]; }
    bc[o] = sl; bc[40+o] = sr + b2[o];
  }
}

template<int K>
__global__ __launch_bounds__(256) void k_buildwt(const float* __restrict__ W1, const float* __restrict__ W2,
                                                 float* __restrict__ dst) {
  int idx = blockIdx.x * 256 + threadIdx.x;
  if (idx >= K*128) return;
  int c = idx & 127, k = idx >> 7;
  dst[idx] = (c < 64) ? W1[c*K + k] : W2[(c-64)*K + k];
}

__global__ __launch_bounds__(256) void k_buildwtf(const float* __restrict__ Wl2, const float* __restrict__ Wr2,
                                                  const float* __restrict__ Wcl, const float* __restrict__ Wcr,
                                                  float* __restrict__ dst) {
  int idx = blockIdx.x * 256 + threadIdx.x;
  if (idx >= 192*80) return;
  int c = idx % 80, k = idx / 80;
  float w;
  if (k < 64) w = (c < 40) ? Wl2[c*128 + k] : Wr2[(c-40)*128 + k];
  else        w = (c < 40) ? Wcl[c*128 + k-64] : Wcr[(c-40)*128 + k-64];
  dst[idx] = w;
}

// ------------- dual GEMM: out1 = in@W1.T, out2 = in@W2.T + bias2 -------------
template<int K, bool BN>
__global__ __launch_bounds__(256) void k_gemm_dual(
    const float* __restrict__ in, const float* __restrict__ ss,
    const float* __restrict__ wtg, const float* __restrict__ bias2,
    float* __restrict__ out1, float* __restrict__ out2) {
  __shared__ float wt[K*128];
  __shared__ float xs[32*K];
  const int tx = threadIdx.x;
  for (int i = tx; i < K*32; i += 256) ((f4*)wt)[i] = ((const f4*)wtg)[i];
  const int row0 = blockIdx.x * 32;
  for (int i = tx; i < 32*(K/4); i += 256) {
    int row = i / (K/4), kq = i % (K/4);
    int grow = row0 + row;
    f4 v = {0.f,0.f,0.f,0.f};
    if (grow < N_NODES) {
      v = *(const f4*)&in[grow*K + kq*4];
      if (BN) {
        int c = kq*4;
        v.x = fmaxf(0.f, fmaf(v.x, ss[c+0], ss[K+c+0]));
        v.y = fmaxf(0.f, fmaf(v.y, ss[c+1], ss[K+c+1]));
        v.z = fmaxf(0.f, fmaf(v.z, ss[c+2], ss[K+c+2]));
        v.w = fmaxf(0.f, fmaf(v.w, ss[c+3], ss[K+c+3]));
      }
    }
    *(f4*)&xs[row*K + kq*4] = v;
  }
  __syncthreads();
  const int c0 = (tx & 31) * 4;
  const int r0 = (tx >> 5) * 4;
  float acc[4][4] = {};
  #pragma unroll 4
  for (int k = 0; k < K; ++k) {
    f4 wv = *(const f4*)&wt[k*128 + c0];
    float x0 = xs[(r0+0)*K + k];
    float x1 = xs[(r0+1)*K + k];
    float x2 = xs[(r0+2)*K + k];
    float x3 = xs[(r0+3)*K + k];
    acc[0][0] = fmaf(x0, wv.x, acc[0][0]); acc[0][1] = fmaf(x0, wv.y, acc[0][1]);
    acc[0][2] = fmaf(x0, wv.z, acc[0][2]); acc[0][3] = fmaf(x0, wv.w, acc[0][3]);
    acc[1][0] = fmaf(x1, wv.x, acc[1][0]); acc[1][1] = fmaf(x1, wv.y, acc[1][1]);
    acc[1][2] = fmaf(x1, wv.z, acc[1][2]); acc[1][3] = fmaf(x1, wv.w, acc[1][3]);
    acc[2][0] = fmaf(x2, wv.x, acc[2][0]); acc[2][1] = fmaf(x2, wv.y, acc[2][1]);
    acc[2][2] = fmaf(x2, wv.z, acc[2][2]); acc[2][3] = fmaf(x2, wv.w, acc[2][3]);
    acc[3][0] = fmaf(x3, wv.x, acc[3][0]); acc[3][1] = fmaf(x3, wv.y, acc[3][1]);
    acc[3][2] = fmaf(x3, wv.z, acc[3][2]); acc[3][3] = fmaf(x3, wv.w, acc[3][3]);
  }
  const bool second = (c0 >= 64);
  const int cc = second ? (c0 - 64) : c0;
  f4 bv = {0.f,0.f,0.f,0.f};
  if (second) bv = *(const f4*)&bias2[cc];
  float* __restrict__ outp = second ? out2 : out1;
  #pragma unroll
  for (int r = 0; r < 4; ++r) {
    int grow = row0 + r0 + r;
    if (grow < N_NODES) {
      f4 o;
      o.x = acc[r][0] + bv.x; o.y = acc[r][1] + bv.y;
      o.z = acc[r][2] + bv.z; o.w = acc[r][3] + bv.w;
      *(f4*)&outp[grow*64 + cc] = o;
    }
  }
}

// ------------- final dual GEMM (K=192 via 2 chunks of 96, 80 out channels) -------------
__global__ __launch_bounds__(320) void k_gemm_final(
    const float* __restrict__ hpre, const float* __restrict__ ss,
    const float* __restrict__ af, const float* __restrict__ wtg,
    const float* __restrict__ bc,
    float* __restrict__ yl, float* __restrict__ yr) {
  __shared__ float wt[96*80];
  __shared__ float xs[64*100];
  const int tx = threadIdx.x;
  const int row0 = blockIdx.x * 64;
  const int c0 = (tx % 20) * 4;
  const int r0 = (tx / 20) * 4;
  float acc[4][4] = {};
  for (int chunk = 0; chunk < 2; ++chunk) {
    if (chunk) __syncthreads();
    for (int i = tx; i < 96*20; i += 320) ((f4*)wt)[i] = ((const f4*)(wtg + chunk*96*80))[i];
    for (int i = tx; i < 64*24; i += 320) {
      int row = i / 24, p = i % 24;
      int kg = chunk*96 + p*4;
      int grow = row0 + row;
      f4 v = {0.f,0.f,0.f,0.f};
      if (grow < N_NODES) {
        if (kg < 64) {
          v = *(const f4*)&hpre[grow*64 + kg];
          v.x = fmaxf(0.f, fmaf(v.x, ss[kg+0], ss[64+kg+0]));
          v.y = fmaxf(0.f, fmaf(v.y, ss[kg+1], ss[64+kg+1]));
          v.z = fmaxf(0.f, fmaf(v.z, ss[kg+2], ss[64+kg+2]));
          v.w = fmaxf(0.f, fmaf(v.w, ss[kg+3], ss[64+kg+3]));
        } else {
          v = *(const f4*)&af[grow*128 + kg - 64];
        }
      }
      *(f4*)&xs[row*100 + p*4] = v;
    }
    __syncthreads();
    #pragma unroll 4
    for (int kk = 0; kk < 96; ++kk) {
      f4 wv = *(const f4*)&wt[kk*80 + c0];
      float x0 = xs[(r0+0)*100 + kk];
      float x1 = xs[(r0+1)*100 + kk];
      float x2 = xs[(r0+2)*100 + kk];
      float x3 = xs[(r0+3)*100 + kk];
      acc[0][0] = fmaf(x0, wv.x, acc[0][0]); acc[0][1] = fmaf(x0, wv.y, acc[0][1]);
      acc[0][2] = fmaf(x0, wv.z, acc[0][2]); acc[0][3] = fmaf(x0, wv.w, acc[0][3]);
      acc[1][0] = fmaf(x1, wv.x, acc[1][0]); acc[1][1] = fmaf(x1, wv.y, acc[1][1]);
      acc[1][2] = fmaf(x1, wv.z, acc[1][2]); acc[1][3] = fmaf(x1, wv.w, acc[1][3]);
      acc[2][0] = fmaf(x2, wv.x, acc[2][0]); acc[2][1] = fmaf(x2, wv.y, acc[2][1]);
      acc[2][2] = fmaf(x2, wv.z, acc[2][2]); acc[2][3] = fmaf(x2, wv.w, acc[2][3]);
      acc[3][0] = fmaf(x3, wv.x, acc[3][0]); acc[3][1] = fmaf(x3, wv.y, acc[3][1]);
      acc[3][2] = fmaf(x3, wv.z, acc[3][2]); acc[3][3] = fmaf(x3, wv.w, acc[3][3]);
    }
  }
  const bool second = (c0 >= 40);
  const int cc = second ? (c0 - 40) : c0;
  f4 bv = *(const f4*)&bc[second ? 40 + cc : cc];
  float* __restrict__ outp = second ? yr : yl;
  #pragma unroll
  for (int r = 0; r < 4; ++r) {
    int grow = row0 + r0 + r;
    if (grow < N_NODES) {
      f4 o;
      o.x = acc[r][0] + bv.x; o.y = acc[r][1] + bv.y;
      o.z = acc[r][2] + bv.z; o.w = acc[r][3] + bv.w;
      *(f4*)&outp[grow*40 + cc] = o;
    }
  }
}

// ------------- CSR gather + finalize (+BN stats) -------------
template<bool STATS>
__global__ __launch_bounds__(256) void k_gather64(
    const int* __restrict__ rowptr, const int* __restrict__ srcs,
    const float* __restrict__ y, const float* __restrict__ yr,
    const float* __restrict__ invd, float* __restrict__ hpre, float* __restrict__ stats) {
  __shared__ float ssum[64], ssq[64];
  const int t = threadIdx.x;
  const int lane = t & 63, w = t >> 6;
  if (STATS) { if (t < 64) { ssum[t] = 0.f; ssq[t] = 0.f; } __syncthreads(); }
  const int node0 = blockIdx.x * 16 + w * 4;
  float psum = 0.f, psq = 0.f;
  #pragma unroll
  for (int n = 0; n < 4; ++n) {
    const int node = node0 + n;
    const int beg = rowptr[node], end = rowptr[node + 1];
    float acc = 0.f;
    for (int e = beg; e < end; ++e) {
      int s = srcs[e];
      acc += y[s * 64 + lane];
    }
    float h = fmaf(acc, invd[node], yr[node * 64 + lane]);
    hpre[node * 64 + lane] = h;
    if (STATS) { psum += h; psq += h * h; }
  }
  if (STATS) {
    atomicAdd(&ssum[lane], psum); atomicAdd(&ssq[lane], psq);
    __syncthreads();
    if (t < 64) { atomicAdd(&stats[t], ssum[t]); atomicAdd(&stats[64 + t], ssq[t]); }
  }
}

__global__ void k_bnparams(const float* __restrict__ stats, const float* __restrict__ g,
                           const float* __restrict__ be, float* __restrict__ ss) {
  int c = threadIdx.x; // 64
  float mean = stats[c] * (1.0f / N_NODES);
  float var  = stats[64+c] * (1.0f / N_NODES) - mean*mean;
  float scale = g[c] * rsqrtf(var + 1e-5f);
  ss[c] = scale;
  ss[64+c] = be[c] - mean*scale;
}

// ------------- CSR gather (40ch) + log_softmax fused -------------
__global__ __launch_bounds__(256) void k_gather_out(
    const int* __restrict__ rowptr, const int* __restrict__ srcs,
    const float* __restrict__ y, const float* __restrict__ yr,
    const float* __restrict__ invd, float* __restrict__ out) {
  const int t = threadIdx.x;
  const int lane = t & 63, w = t >> 6;
  const int node0 = blockIdx.x * 16 + w * 4;
  #pragma unroll
  for (int n = 0; n < 4; ++n) {
    const int node = node0 + n;
    const int beg = rowptr[node], end = rowptr[node + 1];
    float acc = 0.f;
    if (lane < 40) {
      for (int e = beg; e < end; ++e) {
        int s = srcs[e];
        acc += y[s * 40 + lane];
      }
    }
    float v = (lane < 40) ? fmaf(acc, invd[node], yr[node * 40 + lane]) : -1e30f;
    float m = v;
    #pragma unroll
    for (int off = 32; off >= 1; off >>= 1) m = fmaxf(m, __shfl_xor(m, off, 64));
    float e_ = (lane < 40) ? __expf(v - m) : 0.f;
    float s_ = e_;
    #pragma unroll
    for (int off = 32; off >= 1; off >>= 1) s_ += __shfl_xor(s_, off, 64);
    if (lane < 40) out[node * 40 + lane] = v - m - __logf(s_);
  }
}

extern "C" void kernel_launch(void* const* d_in, const int* in_sizes, int n_in,
                              void* d_out, int out_size, void* d_ws, size_t ws_size,
                              hipStream_t stream) {
  const float* x   = (const float*)d_in[0];
  const int*   esrc = (const int*)d_in[1];
  const int*   edst = (const int*)d_in[2];
  const float* af  = (const float*)d_in[3];
  const float* Wl0 = (const float*)d_in[4];
  const float* Wr0 = (const float*)d_in[5];
  const float* b0  = (const float*)d_in[6];
  const float* g0  = (const float*)d_in[7];
  const float* be0 = (const float*)d_in[8];
  const float* Wl1 = (const float*)d_in[9];
  const float* Wr1 = (const float*)d_in[10];
  const float* b1  = (const float*)d_in[11];
  const float* g1  = (const float*)d_in[12];
  const float* be1 = (const float*)d_in[13];
  const float* Wf  = (const float*)d_in[14];
  const float* bfv = (const float*)d_in[15];
  const float* Wl2 = (const float*)d_in[16];
  const float* Wr2 = (const float*)d_in[17];
  const float* b2  = (const float*)d_in[18];

  float* ws   = (float*)d_ws;
  float* invd = ws;                          // N
  float* bufA = ws + (size_t)100000;         // N*64 (y stage)
  float* bufB = bufA + (size_t)6400000;      // N*64 (h_pre)
  float* bufC = bufB + (size_t)6400000;      // N*64 (yr stage)
  float* stats = bufC + (size_t)6400000;     // 512
  float* Wcl  = stats + 512;                 // 40*128
  float* Wcr  = Wcl + 5120;                  // 40*128
  float* bc   = Wcr + 5120;                  // 80
  float* WT0  = bc + 80;                     // 128*128
  float* WT1  = WT0 + 16384;                 // 64*128
  float* WTF  = WT1 + 8192;                  // 192*80
  int*   counts = (int*)(WTF + 15360);       // N (aliased as cursor)
  int*   rowptr = counts + 100000;           // N+1
  int*   srcs   = rowptr + 100001;           // E
  int*   blk    = srcs + N_EDGES;            // SCAN_NBLK
  float* out  = (float*)d_out;

  // ---- CSR build (reused by all 3 layers) ----
  hipMemsetAsync(counts, 0, 100000*sizeof(int), stream);
  hipMemsetAsync(stats, 0, 512*sizeof(float), stream);
  k_count<<<6250, 256, 0, stream>>>(edst, counts);
  k_scan_a<<<SCAN_NBLK, 256, 0, stream>>>(counts, blk);
  k_scan_b<<<1, 128, 0, stream>>>(blk);
  k_scan_c<<<SCAN_NBLK, 256, 0, stream>>>(counts, blk, rowptr, counts /*cursor alias*/, invd);
  k_place<<<6250, 256, 0, stream>>>(esrc, edst, counts, srcs);

  k_precomp<<<40, 128, 0, stream>>>(Wl2, Wr2, Wf, bfv, b2, Wcl, Wcr, bc);
  k_buildwt<128><<<64, 256, 0, stream>>>(Wl0, Wr0, WT0);
  k_buildwt<64><<<32, 256, 0, stream>>>(Wl1, Wr1, WT1);
  k_buildwtf<<<60, 256, 0, stream>>>(Wl2, Wr2, Wcl, Wcr, WTF);

  // ---- layer 0 ----
  k_gemm_dual<128,false><<<3125, 256, 0, stream>>>(x, nullptr, WT0, b0, bufA, bufC);
  k_gather64<true><<<6250, 256, 0, stream>>>(rowptr, srcs, bufA, bufC, invd, bufB, stats);
  k_bnparams<<<1, 64, 0, stream>>>(stats, g0, be0, stats + 128);

  // ---- layer 1 ----
  k_gemm_dual<64,true><<<3125, 256, 0, stream>>>(bufB, stats + 128, WT1, b1, bufA, bufC);
  k_gather64<true><<<6250, 256, 0, stream>>>(rowptr, srcs, bufA, bufC, invd, bufB, stats + 256);
  k_bnparams<<<1, 64, 0, stream>>>(stats + 256, g1, be1, stats + 384);

  // ---- final layer (concat folded via precomputed combined weights) ----
  k_gemm_final<<<1563, 320, 0, stream>>>(bufB, stats + 384, af, WTF, bc, bufA, bufC);
  k_gather_out<<<6250, 256, 0, stream>>>(rowptr, srcs, bufA, bufC, invd, out);
}

// Round 4
// 876.695 us; speedup vs baseline: 4.8633x; 1.1918x over previous
//
#include <hip/hip_runtime.h>

#define N_NODES 100000
#define N_EDGES 1600000
#define SCAN_NBLK 98   // ceil(100000/1024)

typedef float4 f4;

// ---------------- CSR build ----------------
__global__ __launch_bounds__(256) void k_count(const int* __restrict__ dst, int* __restrict__ counts) {
  int i = blockIdx.x * 256 + threadIdx.x;
  if (i < N_EDGES) atomicAdd(&counts[dst[i]], 1);
}

// phase A: per-block (1024 elems) reduce
__global__ __launch_bounds__(256) void k_scan_a(const int* __restrict__ counts, int* __restrict__ blk) {
  __shared__ int red[256];
  const int t = threadIdx.x;
  const int base = blockIdx.x * 1024;
  int s = 0;
  #pragma unroll
  for (int i = 0; i < 4; ++i) {
    int idx = base + t + i * 256;
    if (idx < N_NODES) s += counts[idx];
  }
  red[t] = s; __syncthreads();
  for (int off = 128; off >= 1; off >>= 1) {
    if (t < off) red[t] += red[t + off];
    __syncthreads();
  }
  if (t == 0) blk[blockIdx.x] = red[0];
}

// phase B: single block exclusive scan of SCAN_NBLK block sums
__global__ __launch_bounds__(128) void k_scan_b(int* __restrict__ blk) {
  __shared__ int v[128];
  const int t = threadIdx.x;
  int val = (t < SCAN_NBLK) ? blk[t] : 0;
  v[t] = val; __syncthreads();
  for (int off = 1; off < 128; off <<= 1) {
    int a = (t >= off) ? v[t - off] : 0;
    __syncthreads();
    v[t] += a;
    __syncthreads();
  }
  if (t < SCAN_NBLK) blk[t] = v[t] - val;  // exclusive
}

// phase C: per-block scan + offset -> rowptr, cursor, invd
__global__ __launch_bounds__(256) void k_scan_c(const int* __restrict__ counts, const int* __restrict__ blkoff,
                                                int* __restrict__ rowptr, int* __restrict__ cursor,
                                                float* __restrict__ invd) {
  __shared__ int ps[256];
  const int t = threadIdx.x;
  const int base = blockIdx.x * 1024 + t * 4;
  int c[4]; int s = 0;
  #pragma unroll
  for (int i = 0; i < 4; ++i) {
    int idx = base + i;
    c[i] = (idx < N_NODES) ? counts[idx] : 0;
    s += c[i];
  }
  ps[t] = s; __syncthreads();
  for (int off = 1; off < 256; off <<= 1) {
    int a = (t >= off) ? ps[t - off] : 0;
    __syncthreads();
    ps[t] += a;
    __syncthreads();
  }
  int run = blkoff[blockIdx.x] + ps[t] - s;
  #pragma unroll
  for (int i = 0; i < 4; ++i) {
    int idx = base + i;
    if (idx < N_NODES) {
      rowptr[idx] = run;
      cursor[idx] = run;          // cursor may alias counts: c[] already read
      invd[idx] = 1.0f / fmaxf((float)c[i], 1.0f);
      run += c[i];
      if (idx == N_NODES - 1) rowptr[N_NODES] = run;
    }
  }
}

__global__ __launch_bounds__(256) void k_place(const int* __restrict__ src, const int* __restrict__ dst,
                                               int* __restrict__ cursor, int* __restrict__ srcs) {
  int e = blockIdx.x * 256 + threadIdx.x;
  if (e < N_EDGES) {
    int pos = atomicAdd(&cursor[dst[e]], 1);
    srcs[pos] = src[e];
  }
}

// ------------- combined projection weights for final layer -------------
__global__ void k_precomp(const float* __restrict__ Wl2, const float* __restrict__ Wr2,
                          const float* __restrict__ Wf, const float* __restrict__ bfv,
                          const float* __restrict__ b2,
                          float* __restrict__ Wcl, float* __restrict__ Wcr, float* __restrict__ bc) {
  int o = blockIdx.x, k = threadIdx.x;  // o<40, k<128
  float al = 0.f, ar = 0.f;
  for (int j = 0; j < 64; ++j) {
    float wl = Wl2[o*128 + 64 + j], wr = Wr2[o*128 + 64 + j];
    float wf = Wf[j*128 + k];
    al = fmaf(wl, wf, al); ar = fmaf(wr, wf, ar);
  }
  Wcl[o*128 + k] = al; Wcr[o*128 + k] = ar;
  if (k == 0) {
    float sl = 0.f, sr = 0.f;
    for (int j = 0; j < 64; ++j) { sl += Wl2[o*128+64+j]*bfv[j]; sr += Wr2[o*128+64+j]*bfv[j]; }
    bc[o] = sl; bc[40+o] = sr + b2[o];
  }
}

template<int K>
__global__ __launch_bounds__(256) void k_buildwt(const float* __restrict__ W1, const float* __restrict__ W2,
                                                 float* __restrict__ dst) {
  int idx = blockIdx.x * 256 + threadIdx.x;
  if (idx >= K*128) return;
  int c = idx & 127, k = idx >> 7;
  dst[idx] = (c < 64) ? W1[c*K + k] : W2[(c-64)*K + k];
}

__global__ __launch_bounds__(256) void k_buildwtf(const float* __restrict__ Wl2, const float* __restrict__ Wr2,
                                                  const float* __restrict__ Wcl, const float* __restrict__ Wcr,
                                                  float* __restrict__ dst) {
  int idx = blockIdx.x * 256 + threadIdx.x;
  if (idx >= 192*80) return;
  int c = idx % 80, k = idx / 80;
  float w;
  if (k < 64) w = (c < 40) ? Wl2[c*128 + k] : Wr2[(c-40)*128 + k];
  else        w = (c < 40) ? Wcl[c*128 + k-64] : Wcr[(c-40)*128 + k-64];
  dst[idx] = w;
}

// ------------- dual GEMM: out1 = in@W1.T, out2 = in@W2.T + bias2 -------------
template<int K, bool BN>
__global__ __launch_bounds__(256) void k_gemm_dual(
    const float* __restrict__ in, const float* __restrict__ ss,
    const float* __restrict__ wtg, const float* __restrict__ bias2,
    float* __restrict__ out1, float* __restrict__ out2) {
  __shared__ float wt[K*128];
  __shared__ float xs[32*K];
  const int tx = threadIdx.x;
  for (int i = tx; i < K*32; i += 256) ((f4*)wt)[i] = ((const f4*)wtg)[i];
  const int row0 = blockIdx.x * 32;
  for (int i = tx; i < 32*(K/4); i += 256) {
    int row = i / (K/4), kq = i % (K/4);
    int grow = row0 + row;
    f4 v = {0.f,0.f,0.f,0.f};
    if (grow < N_NODES) {
      v = *(const f4*)&in[grow*K + kq*4];
      if (BN) {
        int c = kq*4;
        v.x = fmaxf(0.f, fmaf(v.x, ss[c+0], ss[K+c+0]));
        v.y = fmaxf(0.f, fmaf(v.y, ss[c+1], ss[K+c+1]));
        v.z = fmaxf(0.f, fmaf(v.z, ss[c+2], ss[K+c+2]));
        v.w = fmaxf(0.f, fmaf(v.w, ss[c+3], ss[K+c+3]));
      }
    }
    *(f4*)&xs[row*K + kq*4] = v;
  }
  __syncthreads();
  const int c0 = (tx & 31) * 4;
  const int r0 = (tx >> 5) * 4;
  float acc[4][4] = {};
  #pragma unroll 4
  for (int k = 0; k < K; ++k) {
    f4 wv = *(const f4*)&wt[k*128 + c0];
    float x0 = xs[(r0+0)*K + k];
    float x1 = xs[(r0+1)*K + k];
    float x2 = xs[(r0+2)*K + k];
    float x3 = xs[(r0+3)*K + k];
    acc[0][0] = fmaf(x0, wv.x, acc[0][0]); acc[0][1] = fmaf(x0, wv.y, acc[0][1]);
    acc[0][2] = fmaf(x0, wv.z, acc[0][2]); acc[0][3] = fmaf(x0, wv.w, acc[0][3]);
    acc[1][0] = fmaf(x1, wv.x, acc[1][0]); acc[1][1] = fmaf(x1, wv.y, acc[1][1]);
    acc[1][2] = fmaf(x1, wv.z, acc[1][2]); acc[1][3] = fmaf(x1, wv.w, acc[1][3]);
    acc[2][0] = fmaf(x2, wv.x, acc[2][0]); acc[2][1] = fmaf(x2, wv.y, acc[2][1]);
    acc[2][2] = fmaf(x2, wv.z, acc[2][2]); acc[2][3] = fmaf(x2, wv.w, acc[2][3]);
    acc[3][0] = fmaf(x3, wv.x, acc[3][0]); acc[3][1] = fmaf(x3, wv.y, acc[3][1]);
    acc[3][2] = fmaf(x3, wv.z, acc[3][2]); acc[3][3] = fmaf(x3, wv.w, acc[3][3]);
  }
  const bool second = (c0 >= 64);
  const int cc = second ? (c0 - 64) : c0;
  f4 bv = {0.f,0.f,0.f,0.f};
  if (second) bv = *(const f4*)&bias2[cc];
  float* __restrict__ outp = second ? out2 : out1;
  #pragma unroll
  for (int r = 0; r < 4; ++r) {
    int grow = row0 + r0 + r;
    if (grow < N_NODES) {
      f4 o;
      o.x = acc[r][0] + bv.x; o.y = acc[r][1] + bv.y;
      o.z = acc[r][2] + bv.z; o.w = acc[r][3] + bv.w;
      *(f4*)&outp[grow*64 + cc] = o;
    }
  }
}

// ------------- final dual GEMM (K=192 via 2 chunks of 96, 80 out channels) -------------
__global__ __launch_bounds__(320) void k_gemm_final(
    const float* __restrict__ hpre, const float* __restrict__ ss,
    const float* __restrict__ af, const float* __restrict__ wtg,
    const float* __restrict__ bc,
    float* __restrict__ yl, float* __restrict__ yr) {
  __shared__ float wt[96*80];
  __shared__ float xs[64*100];
  const int tx = threadIdx.x;
  const int row0 = blockIdx.x * 64;
  const int c0 = (tx % 20) * 4;
  const int r0 = (tx / 20) * 4;
  float acc[4][4] = {};
  for (int chunk = 0; chunk < 2; ++chunk) {
    if (chunk) __syncthreads();
    for (int i = tx; i < 96*20; i += 320) ((f4*)wt)[i] = ((const f4*)(wtg + chunk*96*80))[i];
    for (int i = tx; i < 64*24; i += 320) {
      int row = i / 24, p = i % 24;
      int kg = chunk*96 + p*4;
      int grow = row0 + row;
      f4 v = {0.f,0.f,0.f,0.f};
      if (grow < N_NODES) {
        if (kg < 64) {
          v = *(const f4*)&hpre[grow*64 + kg];
          v.x = fmaxf(0.f, fmaf(v.x, ss[kg+0], ss[64+kg+0]));
          v.y = fmaxf(0.f, fmaf(v.y, ss[kg+1], ss[64+kg+1]));
          v.z = fmaxf(0.f, fmaf(v.z, ss[kg+2], ss[64+kg+2]));
          v.w = fmaxf(0.f, fmaf(v.w, ss[kg+3], ss[64+kg+3]));
        } else {
          v = *(const f4*)&af[grow*128 + kg - 64];
        }
      }
      *(f4*)&xs[row*100 + p*4] = v;
    }
    __syncthreads();
    #pragma unroll 4
    for (int kk = 0; kk < 96; ++kk) {
      f4 wv = *(const f4*)&wt[kk*80 + c0];
      float x0 = xs[(r0+0)*100 + kk];
      float x1 = xs[(r0+1)*100 + kk];
      float x2 = xs[(r0+2)*100 + kk];
      float x3 = xs[(r0+3)*100 + kk];
      acc[0][0] = fmaf(x0, wv.x, acc[0][0]); acc[0][1] = fmaf(x0, wv.y, acc[0][1]);
      acc[0][2] = fmaf(x0, wv.z, acc[0][2]); acc[0][3] = fmaf(x0, wv.w, acc[0][3]);
      acc[1][0] = fmaf(x1, wv.x, acc[1][0]); acc[1][1] = fmaf(x1, wv.y, acc[1][1]);
      acc[1][2] = fmaf(x1, wv.z, acc[1][2]); acc[1][3] = fmaf(x1, wv.w, acc[1][3]);
      acc[2][0] = fmaf(x2, wv.x, acc[2][0]); acc[2][1] = fmaf(x2, wv.y, acc[2][1]);
      acc[2][2] = fmaf(x2, wv.z, acc[2][2]); acc[2][3] = fmaf(x2, wv.w, acc[2][3]);
      acc[3][0] = fmaf(x3, wv.x, acc[3][0]); acc[3][1] = fmaf(x3, wv.y, acc[3][1]);
      acc[3][2] = fmaf(x3, wv.z, acc[3][2]); acc[3][3] = fmaf(x3, wv.w, acc[3][3]);
    }
  }
  const bool second = (c0 >= 40);
  const int cc = second ? (c0 - 40) : c0;
  f4 bv = *(const f4*)&bc[second ? 40 + cc : cc];
  float* __restrict__ outp = second ? yr : yl;
  #pragma unroll
  for (int r = 0; r < 4; ++r) {
    int grow = row0 + r0 + r;
    if (grow < N_NODES) {
      f4 o;
      o.x = acc[r][0] + bv.x; o.y = acc[r][1] + bv.y;
      o.z = acc[r][2] + bv.z; o.w = acc[r][3] + bv.w;
      *(f4*)&outp[grow*40 + cc] = o;
    }
  }
}

// ------------- CSR gather + finalize (+BN stats), 8-deep MLP -------------
template<bool STATS>
__global__ __launch_bounds__(256) void k_gather64(
    const int* __restrict__ rowptr, const int* __restrict__ srcs,
    const float* __restrict__ y, const float* __restrict__ yr,
    const float* __restrict__ invd, float* __restrict__ hpre, float* __restrict__ stats) {
  __shared__ float ssum[64], ssq[64];
  const int t = threadIdx.x;
  const int lane = t & 63, w = t >> 6;
  if (STATS) { if (t < 64) { ssum[t] = 0.f; ssq[t] = 0.f; } __syncthreads(); }
  const int node0 = blockIdx.x * 16 + w * 4;
  float psum = 0.f, psq = 0.f;
  #pragma unroll
  for (int n = 0; n < 4; ++n) {
    const int node = node0 + n;
    const int beg = rowptr[node], end = rowptr[node + 1];
    float acc = 0.f;
    int e = beg;
    for (; e + 8 <= end; e += 8) {
      int s0 = srcs[e+0], s1 = srcs[e+1], s2 = srcs[e+2], s3 = srcs[e+3];
      int s4 = srcs[e+4], s5 = srcs[e+5], s6 = srcs[e+6], s7 = srcs[e+7];
      float v0 = y[s0*64 + lane];
      float v1 = y[s1*64 + lane];
      float v2 = y[s2*64 + lane];
      float v3 = y[s3*64 + lane];
      float v4 = y[s4*64 + lane];
      float v5 = y[s5*64 + lane];
      float v6 = y[s6*64 + lane];
      float v7 = y[s7*64 + lane];
      acc += ((v0 + v1) + (v2 + v3)) + ((v4 + v5) + (v6 + v7));
    }
    for (; e < end; ++e) acc += y[srcs[e]*64 + lane];
    float h = fmaf(acc, invd[node], yr[node * 64 + lane]);
    hpre[node * 64 + lane] = h;
    if (STATS) { psum += h; psq += h * h; }
  }
  if (STATS) {
    atomicAdd(&ssum[lane], psum); atomicAdd(&ssq[lane], psq);
    __syncthreads();
    if (t < 64) { atomicAdd(&stats[t], ssum[t]); atomicAdd(&stats[64 + t], ssq[t]); }
  }
}

__global__ void k_bnparams(const float* __restrict__ stats, const float* __restrict__ g,
                           const float* __restrict__ be, float* __restrict__ ss) {
  int c = threadIdx.x; // 64
  float mean = stats[c] * (1.0f / N_NODES);
  float var  = stats[64+c] * (1.0f / N_NODES) - mean*mean;
  float scale = g[c] * rsqrtf(var + 1e-5f);
  ss[c] = scale;
  ss[64+c] = be[c] - mean*scale;
}

// ------------- CSR gather (40ch) + log_softmax fused, 8-deep MLP -------------
__global__ __launch_bounds__(256) void k_gather_out(
    const int* __restrict__ rowptr, const int* __restrict__ srcs,
    const float* __restrict__ y, const float* __restrict__ yr,
    const float* __restrict__ invd, float* __restrict__ out) {
  const int t = threadIdx.x;
  const int lane = t & 63, w = t >> 6;
  const int node0 = blockIdx.x * 16 + w * 4;
  #pragma unroll
  for (int n = 0; n < 4; ++n) {
    const int node = node0 + n;
    const int beg = rowptr[node], end = rowptr[node + 1];
    float acc = 0.f;
    if (lane < 40) {
      int e = beg;
      for (; e + 8 <= end; e += 8) {
        int s0 = srcs[e+0], s1 = srcs[e+1], s2 = srcs[e+2], s3 = srcs[e+3];
        int s4 = srcs[e+4], s5 = srcs[e+5], s6 = srcs[e+6], s7 = srcs[e+7];
        float v0 = y[s0*40 + lane];
        float v1 = y[s1*40 + lane];
        float v2 = y[s2*40 + lane];
        float v3 = y[s3*40 + lane];
        float v4 = y[s4*40 + lane];
        float v5 = y[s5*40 + lane];
        float v6 = y[s6*40 + lane];
        float v7 = y[s7*40 + lane];
        acc += ((v0 + v1) + (v2 + v3)) + ((v4 + v5) + (v6 + v7));
      }
      for (; e < end; ++e) acc += y[srcs[e]*40 + lane];
    }
    float v = (lane < 40) ? fmaf(acc, invd[node], yr[node * 40 + lane]) : -1e30f;
    float m = v;
    #pragma unroll
    for (int off = 32; off >= 1; off >>= 1) m = fmaxf(m, __shfl_xor(m, off, 64));
    float e_ = (lane < 40) ? __expf(v - m) : 0.f;
    float s_ = e_;
    #pragma unroll
    for (int off = 32; off >= 1; off >>= 1) s_ += __shfl_xor(s_, off, 64);
    if (lane < 40) out[node * 40 + lane] = v - m - __logf(s_);
  }
}

extern "C" void kernel_launch(void* const* d_in, const int* in_sizes, int n_in,
                              void* d_out, int out_size, void* d_ws, size_t ws_size,
                              hipStream_t stream) {
  const float* x   = (const float*)d_in[0];
  const int*   esrc = (const int*)d_in[1];
  const int*   edst = (const int*)d_in[2];
  const float* af  = (const float*)d_in[3];
  const float* Wl0 = (const float*)d_in[4];
  const float* Wr0 = (const float*)d_in[5];
  const float* b0  = (const float*)d_in[6];
  const float* g0  = (const float*)d_in[7];
  const float* be0 = (const float*)d_in[8];
  const float* Wl1 = (const float*)d_in[9];
  const float* Wr1 = (const float*)d_in[10];
  const float* b1  = (const float*)d_in[11];
  const float* g1  = (const float*)d_in[12];
  const float* be1 = (const float*)d_in[13];
  const float* Wf  = (const float*)d_in[14];
  const float* bfv = (const float*)d_in[15];
  const float* Wl2 = (const float*)d_in[16];
  const float* Wr2 = (const float*)d_in[17];
  const float* b2  = (const float*)d_in[18];

  float* ws   = (float*)d_ws;
  float* invd = ws;                          // N
  float* bufA = ws + (size_t)100000;         // N*64 (y stage)
  float* bufB = bufA + (size_t)6400000;      // N*64 (h_pre)
  float* bufC = bufB + (size_t)6400000;      // N*64 (yr stage)
  float* stats = bufC + (size_t)6400000;     // 512
  float* Wcl  = stats + 512;                 // 40*128
  float* Wcr  = Wcl + 5120;                  // 40*128
  float* bc   = Wcr + 5120;                  // 80
  float* WT0  = bc + 80;                     // 128*128
  float* WT1  = WT0 + 16384;                 // 64*128
  float* WTF  = WT1 + 8192;                  // 192*80
  int*   counts = (int*)(WTF + 15360);       // N (aliased as cursor)
  int*   rowptr = counts + 100000;           // N+1
  int*   srcs   = rowptr + 100001;           // E
  int*   blk    = srcs + N_EDGES;            // SCAN_NBLK
  float* out  = (float*)d_out;

  // ---- CSR build (reused by all 3 layers) ----
  hipMemsetAsync(counts, 0, 100000*sizeof(int), stream);
  hipMemsetAsync(stats, 0, 512*sizeof(float), stream);
  k_count<<<6250, 256, 0, stream>>>(edst, counts);
  k_scan_a<<<SCAN_NBLK, 256, 0, stream>>>(counts, blk);
  k_scan_b<<<1, 128, 0, stream>>>(blk);
  k_scan_c<<<SCAN_NBLK, 256, 0, stream>>>(counts, blk, rowptr, counts /*cursor alias*/, invd);
  k_place<<<6250, 256, 0, stream>>>(esrc, edst, counts, srcs);

  k_precomp<<<40, 128, 0, stream>>>(Wl2, Wr2, Wf, bfv, b2, Wcl, Wcr, bc);
  k_buildwt<128><<<64, 256, 0, stream>>>(Wl0, Wr0, WT0);
  k_buildwt<64><<<32, 256, 0, stream>>>(Wl1, Wr1, WT1);
  k_buildwtf<<<60, 256, 0, stream>>>(Wl2, Wr2, Wcl, Wcr, WTF);

  // ---- layer 0 ----
  k_gemm_dual<128,false><<<3125, 256, 0, stream>>>(x, nullptr, WT0, b0, bufA, bufC);
  k_gather64<true><<<6250, 256, 0, stream>>>(rowptr, srcs, bufA, bufC, invd, bufB, stats);
  k_bnparams<<<1, 64, 0, stream>>>(stats, g0, be0, stats + 128);

  // ---- layer 1 ----
  k_gemm_dual<64,true><<<3125, 256, 0, stream>>>(bufB, stats + 128, WT1, b1, bufA, bufC);
  k_gather64<true><<<6250, 256, 0, stream>>>(rowptr, srcs, bufA, bufC, invd, bufB, stats + 256);
  k_bnparams<<<1, 64, 0, stream>>>(stats + 256, g1, be1, stats + 384);

  // ---- final layer (concat folded via precomputed combined weights) ----
  k_gemm_final<<<1563, 320, 0, stream>>>(bufB, stats + 384, af, WTF, bc, bufA, bufC);
  k_gather_out<<<6250, 256, 0, stream>>>(rowptr, srcs, bufA, bufC, invd, out);
}

// Round 5
// 839.968 us; speedup vs baseline: 5.0759x; 1.0437x over previous
//
#include <hip/hip_runtime.h>

#define N_NODES 100000
#define N_EDGES 1600000
#define SCAN_NBLK 98   // ceil(100000/1024)

typedef float4 f4;

__device__ __forceinline__ float bf2f(unsigned short v) {
  return __uint_as_float(((unsigned)v) << 16);
}
__device__ __forceinline__ unsigned short f2bf(float f) {
  unsigned u = __float_as_uint(f);
  u += 0x7FFF + ((u >> 16) & 1);   // round-to-nearest-even
  return (unsigned short)(u >> 16);
}

// ---------------- CSR build ----------------
__global__ __launch_bounds__(256) void k_count(const int* __restrict__ dst, int* __restrict__ counts) {
  int i = blockIdx.x * 256 + threadIdx.x;
  if (i < N_EDGES) atomicAdd(&counts[dst[i]], 1);
}

__global__ __launch_bounds__(256) void k_scan_a(const int* __restrict__ counts, int* __restrict__ blk) {
  __shared__ int red[256];
  const int t = threadIdx.x;
  const int base = blockIdx.x * 1024;
  int s = 0;
  #pragma unroll
  for (int i = 0; i < 4; ++i) {
    int idx = base + t + i * 256;
    if (idx < N_NODES) s += counts[idx];
  }
  red[t] = s; __syncthreads();
  for (int off = 128; off >= 1; off >>= 1) {
    if (t < off) red[t] += red[t + off];
    __syncthreads();
  }
  if (t == 0) blk[blockIdx.x] = red[0];
}

__global__ __launch_bounds__(128) void k_scan_b(int* __restrict__ blk) {
  __shared__ int v[128];
  const int t = threadIdx.x;
  int val = (t < SCAN_NBLK) ? blk[t] : 0;
  v[t] = val; __syncthreads();
  for (int off = 1; off < 128; off <<= 1) {
    int a = (t >= off) ? v[t - off] : 0;
    __syncthreads();
    v[t] += a;
    __syncthreads();
  }
  if (t < SCAN_NBLK) blk[t] = v[t] - val;  // exclusive
}

__global__ __launch_bounds__(256) void k_scan_c(const int* __restrict__ counts, const int* __restrict__ blkoff,
                                                int* __restrict__ rowptr, int* __restrict__ cursor,
                                                float* __restrict__ invd) {
  __shared__ int ps[256];
  const int t = threadIdx.x;
  const int base = blockIdx.x * 1024 + t * 4;
  int c[4]; int s = 0;
  #pragma unroll
  for (int i = 0; i < 4; ++i) {
    int idx = base + i;
    c[i] = (idx < N_NODES) ? counts[idx] : 0;
    s += c[i];
  }
  ps[t] = s; __syncthreads();
  for (int off = 1; off < 256; off <<= 1) {
    int a = (t >= off) ? ps[t - off] : 0;
    __syncthreads();
    ps[t] += a;
    __syncthreads();
  }
  int run = blkoff[blockIdx.x] + ps[t] - s;
  #pragma unroll
  for (int i = 0; i < 4; ++i) {
    int idx = base + i;
    if (idx < N_NODES) {
      rowptr[idx] = run;
      cursor[idx] = run;
      invd[idx] = 1.0f / fmaxf((float)c[i], 1.0f);
      run += c[i];
      if (idx == N_NODES - 1) rowptr[N_NODES] = run;
    }
  }
}

__global__ __launch_bounds__(256) void k_place(const int* __restrict__ src, const int* __restrict__ dst,
                                               int* __restrict__ cursor, int* __restrict__ srcs) {
  int e = blockIdx.x * 256 + threadIdx.x;
  if (e < N_EDGES) {
    int pos = atomicAdd(&cursor[dst[e]], 1);
    srcs[pos] = src[e];
  }
}

// ------------- combined projection weights for final layer -------------
__global__ void k_precomp(const float* __restrict__ Wl2, const float* __restrict__ Wr2,
                          const float* __restrict__ Wf, const float* __restrict__ bfv,
                          const float* __restrict__ b2,
                          float* __restrict__ Wcl, float* __restrict__ Wcr, float* __restrict__ bc) {
  int o = blockIdx.x, k = threadIdx.x;  // o<40, k<128
  float al = 0.f, ar = 0.f;
  for (int j = 0; j < 64; ++j) {
    float wl = Wl2[o*128 + 64 + j], wr = Wr2[o*128 + 64 + j];
    float wf = Wf[j*128 + k];
    al = fmaf(wl, wf, al); ar = fmaf(wr, wf, ar);
  }
  Wcl[o*128 + k] = al; Wcr[o*128 + k] = ar;
  if (k == 0) {
    float sl = 0.f, sr = 0.f;
    for (int j = 0; j < 64; ++j) { sl += Wl2[o*128+64+j]*bfv[j]; sr += Wr2[o*128+64+j]*bfv[j]; }
    bc[o] = sl; bc[40+o] = sr + b2[o];
  }
}

template<int K>
__global__ __launch_bounds__(256) void k_buildwt(const float* __restrict__ W1, const float* __restrict__ W2,
                                                 float* __restrict__ dst) {
  int idx = blockIdx.x * 256 + threadIdx.x;
  if (idx >= K*128) return;
  int c = idx & 127, k = idx >> 7;
  dst[idx] = (c < 64) ? W1[c*K + k] : W2[(c-64)*K + k];
}

__global__ __launch_bounds__(256) void k_buildwtf(const float* __restrict__ Wl2, const float* __restrict__ Wr2,
                                                  const float* __restrict__ Wcl, const float* __restrict__ Wcr,
                                                  float* __restrict__ dst) {
  int idx = blockIdx.x * 256 + threadIdx.x;
  if (idx >= 192*80) return;
  int c = idx % 80, k = idx / 80;
  float w;
  if (k < 64) w = (c < 40) ? Wl2[c*128 + k] : Wr2[(c-40)*128 + k];
  else        w = (c < 40) ? Wcl[c*128 + k-64] : Wcr[(c-40)*128 + k-64];
  dst[idx] = w;
}

// ------------- dual GEMM: out1(bf16) = in@W1.T, out2(f32) = in@W2.T + bias2 -------------
template<int K, bool BN>
__global__ __launch_bounds__(256) void k_gemm_dual(
    const float* __restrict__ in, const float* __restrict__ ss,
    const float* __restrict__ wtg, const float* __restrict__ bias2,
    unsigned short* __restrict__ out1, float* __restrict__ out2) {
  __shared__ float wt[K*128];
  __shared__ float xs[32*K];
  const int tx = threadIdx.x;
  for (int i = tx; i < K*32; i += 256) ((f4*)wt)[i] = ((const f4*)wtg)[i];
  const int row0 = blockIdx.x * 32;
  for (int i = tx; i < 32*(K/4); i += 256) {
    int row = i / (K/4), kq = i % (K/4);
    int grow = row0 + row;
    f4 v = {0.f,0.f,0.f,0.f};
    if (grow < N_NODES) {
      v = *(const f4*)&in[grow*K + kq*4];
      if (BN) {
        int c = kq*4;
        v.x = fmaxf(0.f, fmaf(v.x, ss[c+0], ss[K+c+0]));
        v.y = fmaxf(0.f, fmaf(v.y, ss[c+1], ss[K+c+1]));
        v.z = fmaxf(0.f, fmaf(v.z, ss[c+2], ss[K+c+2]));
        v.w = fmaxf(0.f, fmaf(v.w, ss[c+3], ss[K+c+3]));
      }
    }
    *(f4*)&xs[row*K + kq*4] = v;
  }
  __syncthreads();
  const int c0 = (tx & 31) * 4;
  const int r0 = (tx >> 5) * 4;
  float acc[4][4] = {};
  #pragma unroll 4
  for (int k = 0; k < K; ++k) {
    f4 wv = *(const f4*)&wt[k*128 + c0];
    float x0 = xs[(r0+0)*K + k];
    float x1 = xs[(r0+1)*K + k];
    float x2 = xs[(r0+2)*K + k];
    float x3 = xs[(r0+3)*K + k];
    acc[0][0] = fmaf(x0, wv.x, acc[0][0]); acc[0][1] = fmaf(x0, wv.y, acc[0][1]);
    acc[0][2] = fmaf(x0, wv.z, acc[0][2]); acc[0][3] = fmaf(x0, wv.w, acc[0][3]);
    acc[1][0] = fmaf(x1, wv.x, acc[1][0]); acc[1][1] = fmaf(x1, wv.y, acc[1][1]);
    acc[1][2] = fmaf(x1, wv.z, acc[1][2]); acc[1][3] = fmaf(x1, wv.w, acc[1][3]);
    acc[2][0] = fmaf(x2, wv.x, acc[2][0]); acc[2][1] = fmaf(x2, wv.y, acc[2][1]);
    acc[2][2] = fmaf(x2, wv.z, acc[2][2]); acc[2][3] = fmaf(x2, wv.w, acc[2][3]);
    acc[3][0] = fmaf(x3, wv.x, acc[3][0]); acc[3][1] = fmaf(x3, wv.y, acc[3][1]);
    acc[3][2] = fmaf(x3, wv.z, acc[3][2]); acc[3][3] = fmaf(x3, wv.w, acc[3][3]);
  }
  const bool second = (c0 >= 64);
  if (second) {
    const int cc = c0 - 64;
    f4 bv = *(const f4*)&bias2[cc];
    #pragma unroll
    for (int r = 0; r < 4; ++r) {
      int grow = row0 + r0 + r;
      if (grow < N_NODES) {
        f4 o;
        o.x = acc[r][0] + bv.x; o.y = acc[r][1] + bv.y;
        o.z = acc[r][2] + bv.z; o.w = acc[r][3] + bv.w;
        *(f4*)&out2[grow*64 + cc] = o;
      }
    }
  } else {
    #pragma unroll
    for (int r = 0; r < 4; ++r) {
      int grow = row0 + r0 + r;
      if (grow < N_NODES) {
        ushort4 o;
        o.x = f2bf(acc[r][0]); o.y = f2bf(acc[r][1]);
        o.z = f2bf(acc[r][2]); o.w = f2bf(acc[r][3]);
        *(ushort4*)&out1[grow*64 + c0] = o;
      }
    }
  }
}

// ------------- final dual GEMM (K=192 via 2 chunks of 96, 80 out channels) -------------
__global__ __launch_bounds__(320) void k_gemm_final(
    const float* __restrict__ hpre, const float* __restrict__ ss,
    const float* __restrict__ af, const float* __restrict__ wtg,
    const float* __restrict__ bc,
    float* __restrict__ yl, float* __restrict__ yr) {
  __shared__ float wt[96*80];
  __shared__ float xs[64*100];
  const int tx = threadIdx.x;
  const int row0 = blockIdx.x * 64;
  const int c0 = (tx % 20) * 4;
  const int r0 = (tx / 20) * 4;
  float acc[4][4] = {};
  for (int chunk = 0; chunk < 2; ++chunk) {
    if (chunk) __syncthreads();
    for (int i = tx; i < 96*20; i += 320) ((f4*)wt)[i] = ((const f4*)(wtg + chunk*96*80))[i];
    for (int i = tx; i < 64*24; i += 320) {
      int row = i / 24, p = i % 24;
      int kg = chunk*96 + p*4;
      int grow = row0 + row;
      f4 v = {0.f,0.f,0.f,0.f};
      if (grow < N_NODES) {
        if (kg < 64) {
          v = *(const f4*)&hpre[grow*64 + kg];
          v.x = fmaxf(0.f, fmaf(v.x, ss[kg+0], ss[64+kg+0]));
          v.y = fmaxf(0.f, fmaf(v.y, ss[kg+1], ss[64+kg+1]));
          v.z = fmaxf(0.f, fmaf(v.z, ss[kg+2], ss[64+kg+2]));
          v.w = fmaxf(0.f, fmaf(v.w, ss[kg+3], ss[64+kg+3]));
        } else {
          v = *(const f4*)&af[grow*128 + kg - 64];
        }
      }
      *(f4*)&xs[row*100 + p*4] = v;
    }
    __syncthreads();
    #pragma unroll 4
    for (int kk = 0; kk < 96; ++kk) {
      f4 wv = *(const f4*)&wt[kk*80 + c0];
      float x0 = xs[(r0+0)*100 + kk];
      float x1 = xs[(r0+1)*100 + kk];
      float x2 = xs[(r0+2)*100 + kk];
      float x3 = xs[(r0+3)*100 + kk];
      acc[0][0] = fmaf(x0, wv.x, acc[0][0]); acc[0][1] = fmaf(x0, wv.y, acc[0][1]);
      acc[0][2] = fmaf(x0, wv.z, acc[0][2]); acc[0][3] = fmaf(x0, wv.w, acc[0][3]);
      acc[1][0] = fmaf(x1, wv.x, acc[1][0]); acc[1][1] = fmaf(x1, wv.y, acc[1][1]);
      acc[1][2] = fmaf(x1, wv.z, acc[1][2]); acc[1][3] = fmaf(x1, wv.w, acc[1][3]);
      acc[2][0] = fmaf(x2, wv.x, acc[2][0]); acc[2][1] = fmaf(x2, wv.y, acc[2][1]);
      acc[2][2] = fmaf(x2, wv.z, acc[2][2]); acc[2][3] = fmaf(x2, wv.w, acc[2][3]);
      acc[3][0] = fmaf(x3, wv.x, acc[3][0]); acc[3][1] = fmaf(x3, wv.y, acc[3][1]);
      acc[3][2] = fmaf(x3, wv.z, acc[3][2]); acc[3][3] = fmaf(x3, wv.w, acc[3][3]);
    }
  }
  const bool second = (c0 >= 40);
  const int cc = second ? (c0 - 40) : c0;
  f4 bv = *(const f4*)&bc[second ? 40 + cc : cc];
  float* __restrict__ outp = second ? yr : yl;
  #pragma unroll
  for (int r = 0; r < 4; ++r) {
    int grow = row0 + r0 + r;
    if (grow < N_NODES) {
      f4 o;
      o.x = acc[r][0] + bv.x; o.y = acc[r][1] + bv.y;
      o.z = acc[r][2] + bv.z; o.w = acc[r][3] + bv.w;
      *(f4*)&outp[grow*40 + cc] = o;
    }
  }
}

// ------------- CSR gather (bf16 msgs) + finalize (+BN stats), 16/8/4/1 MLP ladder -------------
template<bool STATS>
__global__ __launch_bounds__(256) void k_gather64(
    const int* __restrict__ rowptr, const int* __restrict__ srcs,
    const unsigned short* __restrict__ y, const float* __restrict__ yr,
    const float* __restrict__ invd, float* __restrict__ hpre, float* __restrict__ stats) {
  __shared__ float ssum[64], ssq[64];
  const int t = threadIdx.x;
  const int lane = t & 63, w = t >> 6;
  if (STATS) { if (t < 64) { ssum[t] = 0.f; ssq[t] = 0.f; } __syncthreads(); }
  const int node0 = blockIdx.x * 16 + w * 4;
  float psum = 0.f, psq = 0.f;
  #pragma unroll
  for (int n = 0; n < 4; ++n) {
    const int node = node0 + n;
    const int beg = rowptr[node], end = rowptr[node + 1];
    float acc = 0.f;
    int e = beg;
    for (; e + 16 <= end; e += 16) {
      int s[16];
      #pragma unroll
      for (int i = 0; i < 16; ++i) s[i] = srcs[e + i];
      float v[16];
      #pragma unroll
      for (int i = 0; i < 16; ++i) v[i] = bf2f(y[s[i] * 64 + lane]);
      #pragma unroll
      for (int st = 1; st < 16; st <<= 1)
        #pragma unroll
        for (int i = 0; i < 16; i += 2 * st) v[i] += v[i + st];
      acc += v[0];
    }
    if (e + 8 <= end) {
      int s[8];
      #pragma unroll
      for (int i = 0; i < 8; ++i) s[i] = srcs[e + i];
      float v[8];
      #pragma unroll
      for (int i = 0; i < 8; ++i) v[i] = bf2f(y[s[i] * 64 + lane]);
      acc += ((v[0] + v[1]) + (v[2] + v[3])) + ((v[4] + v[5]) + (v[6] + v[7]));
      e += 8;
    }
    if (e + 4 <= end) {
      int s0 = srcs[e+0], s1 = srcs[e+1], s2 = srcs[e+2], s3 = srcs[e+3];
      float v0 = bf2f(y[s0*64 + lane]);
      float v1 = bf2f(y[s1*64 + lane]);
      float v2 = bf2f(y[s2*64 + lane]);
      float v3 = bf2f(y[s3*64 + lane]);
      acc += (v0 + v1) + (v2 + v3);
      e += 4;
    }
    for (; e < end; ++e) acc += bf2f(y[srcs[e] * 64 + lane]);
    float h = fmaf(acc, invd[node], yr[node * 64 + lane]);
    hpre[node * 64 + lane] = h;
    if (STATS) { psum += h; psq += h * h; }
  }
  if (STATS) {
    atomicAdd(&ssum[lane], psum); atomicAdd(&ssq[lane], psq);
    __syncthreads();
    if (t < 64) { atomicAdd(&stats[t], ssum[t]); atomicAdd(&stats[64 + t], ssq[t]); }
  }
}

__global__ void k_bnparams(const float* __restrict__ stats, const float* __restrict__ g,
                           const float* __restrict__ be, float* __restrict__ ss) {
  int c = threadIdx.x; // 64
  float mean = stats[c] * (1.0f / N_NODES);
  float var  = stats[64+c] * (1.0f / N_NODES) - mean*mean;
  float scale = g[c] * rsqrtf(var + 1e-5f);
  ss[c] = scale;
  ss[64+c] = be[c] - mean*scale;
}

// ------------- CSR gather (40ch f32) + log_softmax fused, 16/8/4/1 ladder -------------
__global__ __launch_bounds__(256) void k_gather_out(
    const int* __restrict__ rowptr, const int* __restrict__ srcs,
    const float* __restrict__ y, const float* __restrict__ yr,
    const float* __restrict__ invd, float* __restrict__ out) {
  const int t = threadIdx.x;
  const int lane = t & 63, w = t >> 6;
  const int node0 = blockIdx.x * 16 + w * 4;
  #pragma unroll
  for (int n = 0; n < 4; ++n) {
    const int node = node0 + n;
    const int beg = rowptr[node], end = rowptr[node + 1];
    float acc = 0.f;
    if (lane < 40) {
      int e = beg;
      for (; e + 16 <= end; e += 16) {
        int s[16];
        #pragma unroll
        for (int i = 0; i < 16; ++i) s[i] = srcs[e + i];
        float v[16];
        #pragma unroll
        for (int i = 0; i < 16; ++i) v[i] = y[s[i] * 40 + lane];
        #pragma unroll
        for (int st = 1; st < 16; st <<= 1)
          #pragma unroll
          for (int i = 0; i < 16; i += 2 * st) v[i] += v[i + st];
        acc += v[0];
      }
      if (e + 8 <= end) {
        int s[8];
        #pragma unroll
        for (int i = 0; i < 8; ++i) s[i] = srcs[e + i];
        float v[8];
        #pragma unroll
        for (int i = 0; i < 8; ++i) v[i] = y[s[i] * 40 + lane];
        acc += ((v[0] + v[1]) + (v[2] + v[3])) + ((v[4] + v[5]) + (v[6] + v[7]));
        e += 8;
      }
      if (e + 4 <= end) {
        int s0 = srcs[e+0], s1 = srcs[e+1], s2 = srcs[e+2], s3 = srcs[e+3];
        float v0 = y[s0*40 + lane];
        float v1 = y[s1*40 + lane];
        float v2 = y[s2*40 + lane];
        float v3 = y[s3*40 + lane];
        acc += (v0 + v1) + (v2 + v3);
        e += 4;
      }
      for (; e < end; ++e) acc += y[srcs[e] * 40 + lane];
    }
    float v = (lane < 40) ? fmaf(acc, invd[node], yr[node * 40 + lane]) : -1e30f;
    float m = v;
    #pragma unroll
    for (int off = 32; off >= 1; off >>= 1) m = fmaxf(m, __shfl_xor(m, off, 64));
    float e_ = (lane < 40) ? __expf(v - m) : 0.f;
    float s_ = e_;
    #pragma unroll
    for (int off = 32; off >= 1; off >>= 1) s_ += __shfl_xor(s_, off, 64);
    if (lane < 40) out[node * 40 + lane] = v - m - __logf(s_);
  }
}

extern "C" void kernel_launch(void* const* d_in, const int* in_sizes, int n_in,
                              void* d_out, int out_size, void* d_ws, size_t ws_size,
                              hipStream_t stream) {
  const float* x   = (const float*)d_in[0];
  const int*   esrc = (const int*)d_in[1];
  const int*   edst = (const int*)d_in[2];
  const float* af  = (const float*)d_in[3];
  const float* Wl0 = (const float*)d_in[4];
  const float* Wr0 = (const float*)d_in[5];
  const float* b0  = (const float*)d_in[6];
  const float* g0  = (const float*)d_in[7];
  const float* be0 = (const float*)d_in[8];
  const float* Wl1 = (const float*)d_in[9];
  const float* Wr1 = (const float*)d_in[10];
  const float* b1  = (const float*)d_in[11];
  const float* g1  = (const float*)d_in[12];
  const float* be1 = (const float*)d_in[13];
  const float* Wf  = (const float*)d_in[14];
  const float* bfv = (const float*)d_in[15];
  const float* Wl2 = (const float*)d_in[16];
  const float* Wr2 = (const float*)d_in[17];
  const float* b2  = (const float*)d_in[18];

  float* ws   = (float*)d_ws;
  float* invd = ws;                          // N
  float* bufA = ws + (size_t)100000;         // N*64 f32 (final yl); first half reused as bf16 msgs
  float* bufB = bufA + (size_t)6400000;      // N*64 (h_pre)
  float* bufC = bufB + (size_t)6400000;      // N*64 (yr stage)
  float* stats = bufC + (size_t)6400000;     // 512
  float* Wcl  = stats + 512;                 // 40*128
  float* Wcr  = Wcl + 5120;                  // 40*128
  float* bc   = Wcr + 5120;                  // 80
  float* WT0  = bc + 80;                     // 128*128
  float* WT1  = WT0 + 16384;                 // 64*128
  float* WTF  = WT1 + 8192;                  // 192*80
  int*   counts = (int*)(WTF + 15360);       // N (aliased as cursor)
  int*   rowptr = counts + 100000;           // N+1
  int*   srcs   = rowptr + 100001;           // E
  int*   blk    = srcs + N_EDGES;            // SCAN_NBLK
  unsigned short* msg = (unsigned short*)bufA;  // N*64 bf16 (aliases bufA; dead before final GEMM writes)
  float* out  = (float*)d_out;

  // ---- CSR build (reused by all 3 layers) ----
  hipMemsetAsync(counts, 0, 100000*sizeof(int), stream);
  hipMemsetAsync(stats, 0, 512*sizeof(float), stream);
  k_count<<<6250, 256, 0, stream>>>(edst, counts);
  k_scan_a<<<SCAN_NBLK, 256, 0, stream>>>(counts, blk);
  k_scan_b<<<1, 128, 0, stream>>>(blk);
  k_scan_c<<<SCAN_NBLK, 256, 0, stream>>>(counts, blk, rowptr, counts /*cursor alias*/, invd);
  k_place<<<6250, 256, 0, stream>>>(esrc, edst, counts, srcs);

  k_precomp<<<40, 128, 0, stream>>>(Wl2, Wr2, Wf, bfv, b2, Wcl, Wcr, bc);
  k_buildwt<128><<<64, 256, 0, stream>>>(Wl0, Wr0, WT0);
  k_buildwt<64><<<32, 256, 0, stream>>>(Wl1, Wr1, WT1);
  k_buildwtf<<<60, 256, 0, stream>>>(Wl2, Wr2, Wcl, Wcr, WTF);

  // ---- layer 0 ----
  k_gemm_dual<128,false><<<3125, 256, 0, stream>>>(x, nullptr, WT0, b0, msg, bufC);
  k_gather64<true><<<6250, 256, 0, stream>>>(rowptr, srcs, msg, bufC, invd, bufB, stats);
  k_bnparams<<<1, 64, 0, stream>>>(stats, g0, be0, stats + 128);

  // ---- layer 1 ----
  k_gemm_dual<64,true><<<3125, 256, 0, stream>>>(bufB, stats + 128, WT1, b1, msg, bufC);
  k_gather64<true><<<6250, 256, 0, stream>>>(rowptr, srcs, msg, bufC, invd, bufB, stats + 256);
  k_bnparams<<<1, 64, 0, stream>>>(stats + 256, g1, be1, stats + 384);

  // ---- final layer (concat folded via precomputed combined weights) ----
  k_gemm_final<<<1563, 320, 0, stream>>>(bufB, stats + 384, af, WTF, bc, bufA, bufC);
  k_gather_out<<<6250, 256, 0, stream>>>(rowptr, srcs, bufA, bufC, invd, out);
}